// Round 6
// baseline (246.084 us; speedup 1.0000x reference)
//
#include <hip/hip_runtime.h>

// ---------------------------------------------------------------------------
// MRLR feature extractor, round 6: wide multi-kernel pipeline.
//   W1 = proj(M^14 C1): S1=M^2*2^-27, S2=S1^2, S3=S2^2, basis Q=S3*S2*S1*C1
//   TMP = M - W1 M; M2 = TMP - TMP W1; W2 = proj(M2^14 (C2 - W1 C2))
//   T = W1 + W2;  out = T X.
// k1: split-K partials (nch WGs/item, 2-hop in-WG ksplit3 reduce)
// k2: reduce partials -> M (unpacked+mirrored) + C
// kw_phase x8: wide 96x96 GEMM phases (12 WGs/item) + optional thin part
// kf_proj x2: per-item Q=S3*P -> Gram -> GJ -> AK -> W (1 WG/item)
// k4: out = T X
// ---------------------------------------------------------------------------

#define TID ((int)threadIdx.x)
typedef float4 f4;

#define SC27 (1.0f/134217728.0f)   // 2^-27

__device__ __forceinline__ f4 ld4(const float* p) { return *(const f4*)p; }
__device__ __forceinline__ void st4(float* p, f4 v) { *(f4*)p = v; }
__device__ __forceinline__ f4 f4zero() { return make_float4(0.f,0.f,0.f,0.f); }
__device__ __forceinline__ f4 add4(f4 a, f4 b){ return make_float4(a.x+b.x,a.y+b.y,a.z+b.z,a.w+b.w); }
__device__ __forceinline__ f4 sub4(f4 a, f4 b){ return make_float4(a.x-b.x,a.y-b.y,a.z-b.z,a.w-b.w); }
__device__ __forceinline__ f4 scl4(f4 a, float s){ return make_float4(a.x*s,a.y*s,a.z*s,a.w*s); }
__device__ __forceinline__ void fma4(f4& a, float s, f4 v) {
  a.x = fmaf(s,v.x,a.x); a.y = fmaf(s,v.y,a.y); a.z = fmaf(s,v.z,a.z); a.w = fmaf(s,v.w,a.w);
}
__device__ __forceinline__ float dot4(f4 a, f4 b, float acc) {
  acc = fmaf(a.x,b.x,acc); acc = fmaf(a.y,b.y,acc);
  acc = fmaf(a.z,b.z,acc); acc = fmaf(a.w,b.w,acc); return acc;
}
__device__ __forceinline__ void trimap(int t, int& ti, int& tj) {
  int rem = t; ti = 0;
  #pragma unroll
  for (int r = 0; r < 12; ++r) { int w = 12 - r; if (rem < w) { ti = r; break; } rem -= w; }
  tj = ti + rem;
}
__device__ __forceinline__ void init8(f4 acc[8][2]) {
  #pragma unroll
  for (int a = 0; a < 8; ++a) { acc[a][0] = f4zero(); acc[a][1] = f4zero(); }
}
__device__ __forceinline__ void tile8_step(f4 acc[8][2], const float* u, const float* v) {
  f4 u0 = ld4(u), u1 = ld4(u+4), v0 = ld4(v), v1 = ld4(v+4);
  float aa[8] = {u0.x,u0.y,u0.z,u0.w,u1.x,u1.y,u1.z,u1.w};
  #pragma unroll
  for (int a = 0; a < 8; ++a) { fma4(acc[a][0], aa[a], v0); fma4(acc[a][1], aa[a], v1); }
}

// ---------------------------------------------------------------------------
// k1: grid (nch, 8), block 512.  450 active: 3 k-parity x (78 tri-M + 72 C).
// 2-hop LDS reduce (red 38.4 KB) -> total LDS 67.6 KB -> 2 WGs/CU at nch=64.
// ---------------------------------------------------------------------------
__global__ __launch_bounds__(512) void k1_partials(
    const float* __restrict__ x, const float* __restrict__ b01,
    const float* __restrict__ b02, float* __restrict__ part,
    int nch, int nsc) {
  __shared__ __align__(16) float Xst[48][100];
  __shared__ __align__(16) float Bs[48][52];
  __shared__ __align__(16) float red[9600];
  int kc = blockIdx.x, item = blockIdx.y;
  const float* X = x + (size_t)item * 96 * 9216;
  float* base = part + (size_t)(item * nch + kc) * 9600;

  int t = TID, kh = 0, tt = 0;
  const float* ap = nullptr; const float* bp = nullptr;
  float* op = nullptr; int os = 0; bool isM = false;
  bool active = (t < 450);
  if (active) {
    kh = t / 150; tt = t % 150;
    if (tt < 78) {
      int ti, tj; trimap(tt, ti, tj);
      ap = &Xst[0][ti*8]; bp = &Xst[0][tj*8];
      op = base + tt*64; os = 8; isM = true;
    } else {
      int u = tt - 78; int i0 = (u/6)*8, c0 = (u%6)*8;
      ap = &Xst[0][i0]; bp = &Bs[0][c0];
      op = base + 4992 + i0*48 + c0; os = 48;
    }
  }

  f4 acc[8][2]; init8(acc);

  for (int sc = 0; sc < nsc; ++sc) {
    int k0 = (kc * nsc + sc) * 48;
    __syncthreads();
    for (int e = TID; e < 1152; e += 512) {          // X slab transposed
      int i = e / 12, kq = (e % 12) * 4;
      f4 v = ld4(&X[(size_t)i * 9216 + k0 + kq]);
      Xst[kq][i] = v.x; Xst[kq+1][i] = v.y; Xst[kq+2][i] = v.z; Xst[kq+3][i] = v.w;
    }
    for (int e = TID; e < 384; e += 512) {           // B01
      int kk = e / 8, cq = (e % 8) * 4;
      st4(&Bs[kk][cq], ld4(&b01[(size_t)(k0 + kk) * 32 + cq]));
    }
    for (int e = TID; e < 192; e += 512) {           // B02
      int kk = e / 4, cq = (e % 4) * 4;
      st4(&Bs[kk][32+cq], ld4(&b02[(size_t)(k0 + kk) * 16 + cq]));
    }
    __syncthreads();
    if (active) {
      int asr = 100, bsr = isM ? 100 : 52;
      const float* ar = ap + kh * asr;
      const float* br = bp + kh * bsr;
      #pragma unroll 4
      for (int kk = kh; kk < 48; kk += 3) {
        tile8_step(acc, ar, br);
        ar += 3 * asr; br += 3 * bsr;
      }
    }
  }
  // 2-hop reduce: kh1 -> red -> kh0; kh2 -> red -> kh0; store.
  __syncthreads();
  if (active && kh == 1) {
    #pragma unroll
    for (int a = 0; a < 8; ++a) { st4(&red[tt*64+a*8], acc[a][0]); st4(&red[tt*64+a*8+4], acc[a][1]); }
  }
  __syncthreads();
  if (active && kh == 0) {
    #pragma unroll
    for (int a = 0; a < 8; ++a) {
      acc[a][0] = add4(acc[a][0], ld4(&red[tt*64+a*8]));
      acc[a][1] = add4(acc[a][1], ld4(&red[tt*64+a*8+4]));
    }
  }
  __syncthreads();
  if (active && kh == 2) {
    #pragma unroll
    for (int a = 0; a < 8; ++a) { st4(&red[tt*64+a*8], acc[a][0]); st4(&red[tt*64+a*8+4], acc[a][1]); }
  }
  __syncthreads();
  if (active && kh == 0) {
    #pragma unroll
    for (int a = 0; a < 8; ++a) {
      f4 s0 = add4(acc[a][0], ld4(&red[tt*64+a*8]));
      f4 s1 = add4(acc[a][1], ld4(&red[tt*64+a*8+4]));
      st4(op + a*os, s0); st4(op + a*os + 4, s1);
    }
  }
}

// ---------------------------------------------------------------------------
// k2: reduce nch partials -> M unpacked (mirrored) + C.  grid 75 x 256.
// ---------------------------------------------------------------------------
__global__ __launch_bounds__(256) void k2_reduce(
    const float* __restrict__ part, float* __restrict__ Mb,
    float* __restrict__ Cb, int nch) {
  int gid = blockIdx.x * 256 + TID;       // < 19200
  int item = gid / 2400, q4 = gid % 2400;
  int off = q4 * 4;
  const float* p = part + (size_t)item * nch * 9600 + off;
  f4 s = f4zero();
  #pragma unroll 8
  for (int c = 0; c < nch; ++c) s = add4(s, ld4(p + (size_t)c * 9600));
  if (off < 4992) {
    int tile = off >> 6, w = (off & 63) >> 2;
    int r = w >> 1, cq = (w & 1) * 4;
    int ti, tj; trimap(tile, ti, tj);
    int i = ti*8 + r, j = tj*8 + cq;
    float* Mi = Mb + (size_t)item * 9216;
    st4(&Mi[i*96 + j], s);
    Mi[(j+0)*96 + i] = s.x; Mi[(j+1)*96 + i] = s.y;
    Mi[(j+2)*96 + i] = s.z; Mi[(j+3)*96 + i] = s.w;
  } else {
    st4(&Cb[(size_t)item * 4608 + (off - 4992)], s);
  }
}

// ---------------------------------------------------------------------------
// kw_phase: wide GEMM phase.  grid (12 or 13, 8), block 256.
// w<12 (square, 192 active): D[r][j] = Sub? Sub[r][j] - (A B)[r][j]
//                                     : scale * (A B)[r][j]
// w==12 (thin, TW cols):     Tout[r][c] = tsub? Tin[r][c] - (A Tin)[r][c]
//                                        : (A Tin)[r][c]
// All A reads are row-major rows (A[r][k]); B/Tin read as rows k (coalesced).
// ---------------------------------------------------------------------------
__global__ __launch_bounds__(256) void kw_phase(
    const float* __restrict__ Ag, const float* __restrict__ Bg,
    const float* __restrict__ Subg, float* __restrict__ Dg, float scale,
    const float* __restrict__ Tin, int ti_istr, int tis, int tsub,
    float* __restrict__ Tout, int to_istr, int tos, int TW) {
  int w = blockIdx.x, item = blockIdx.y;
  const float* A = Ag + (size_t)item * 9216;
  if (w < 12) {
    if (TID >= 192) return;
    const float* B = Bg + (size_t)item * 9216;
    float* D = Dg + (size_t)item * 9216;
    int r = w*8 + TID/24, jb = (TID%24)*4;
    const float* arow = A + r*96;
    f4 acc = f4zero();
    #pragma unroll 8
    for (int k = 0; k < 96; ++k) fma4(acc, arow[k], ld4(&B[k*96 + jb]));
    if (Subg) acc = sub4(ld4(&Subg[(size_t)item*9216 + r*96 + jb]), acc);
    else      acc = scl4(acc, scale);
    st4(&D[r*96 + jb], acc);
  } else {
    int nact = (TW == 32) ? 192 : 96;
    if (TID >= nact) return;
    int r  = (TW == 32) ? (TID >> 1) : TID;
    int c0 = (TW == 32) ? (TID & 1) * 16 : 0;
    const float* Ti = Tin + (size_t)item * ti_istr;
    float* To = Tout + (size_t)item * to_istr;
    const float* arow = A + r*96;
    f4 acc[4] = {f4zero(), f4zero(), f4zero(), f4zero()};
    #pragma unroll 4
    for (int k = 0; k < 96; ++k) {
      float a = arow[k];
      const float* tr = Ti + (size_t)k * tis + c0;
      fma4(acc[0], a, ld4(tr));   fma4(acc[1], a, ld4(tr+4));
      fma4(acc[2], a, ld4(tr+8)); fma4(acc[3], a, ld4(tr+12));
    }
    if (tsub) {
      const float* sr = Ti + (size_t)r * tis + c0;
      #pragma unroll
      for (int u = 0; u < 4; ++u) acc[u] = sub4(ld4(sr + u*4), acc[u]);
    }
    #pragma unroll
    for (int u = 0; u < 4; ++u) st4(&To[(size_t)r * tos + c0 + u*4], acc[u]);
  }
}

// ---------------------------------------------------------------------------
// Gauss-Jordan (unnormalized, double-buffered pivot column), 512 threads.
// ---------------------------------------------------------------------------
__device__ void gauss_jordan(float (*aug)[64], float (*colbuf)[32], int r, int C) {
  int noct = C >> 3;
  int nthr = r * noct;
  __syncthreads();
  if (TID < r) colbuf[0][TID] = aug[TID][0];
  for (int c = 0; c < r; ++c) {
    __syncthreads();
    if (TID < nthr) {
      int i = TID / noct, j0 = (TID % noct) * 8;
      const float* cb = colbuf[c & 1];
      float f = cb[i] / cb[c];
      int nc = c + 1;
      bool own = (nc < r) && (nc >= j0) && (nc < j0 + 8);
      if (i != c) {
        f4 p0 = ld4(&aug[c][j0]), p1 = ld4(&aug[c][j0+4]);
        f4 v0 = ld4(&aug[i][j0]), v1 = ld4(&aug[i][j0+4]);
        float pr[8] = {p0.x,p0.y,p0.z,p0.w,p1.x,p1.y,p1.z,p1.w};
        float vv[8] = {v0.x,v0.y,v0.z,v0.w,v1.x,v1.y,v1.z,v1.w};
        #pragma unroll
        for (int u = 0; u < 8; ++u)
          vv[u] = (j0 + u == c) ? 0.f : fmaf(-f, pr[u], vv[u]);
        st4(&aug[i][j0], make_float4(vv[0],vv[1],vv[2],vv[3]));
        st4(&aug[i][j0+4], make_float4(vv[4],vv[5],vv[6],vv[7]));
        if (own) colbuf[nc & 1][i] = vv[nc - j0];
      } else {
        if (own) colbuf[nc & 1][i] = aug[c][nc];
      }
    }
  }
  __syncthreads();
  int wq = C - r, nq = r * (wq >> 2);
  if (TID < nq) {
    int i = TID / (wq >> 2), jq = (TID % (wq >> 2)) * 4;
    float d = aug[i][i];
    f4 z = ld4(&aug[i][r + jq]);
    z.x /= d; z.y /= d; z.z /= d; z.w /= d;
    st4(&aug[i][r + jq], z);
  }
  __syncthreads();
}

// ---------------------------------------------------------------------------
// kf_proj: per-item fused Q=S3*P -> Gram -> GJ -> AK -> W.  grid(8) x 512.
// mode 1: write W -> W1g.   mode 2: write Tg = W1g + W.
// ---------------------------------------------------------------------------
__global__ __launch_bounds__(512) void kf_proj(
    const float* __restrict__ S3g, const float* __restrict__ Pg, int TW,
    float* __restrict__ W1g, float* __restrict__ Tgg, int mode) {
  __shared__ __align__(16) float Qs[96][32];
  __shared__ __align__(16) float AKs[96][32];
  __shared__ __align__(16) float aug[32][64];
  __shared__ __align__(16) float colbuf[2][32];

  int item = blockIdx.x, t = TID;
  const float* S3 = S3g + (size_t)item * 9216;
  const float* P  = Pg  + (size_t)item * 3072;
  float* W1 = W1g + (size_t)item * 9216;
  float* Tg = Tgg + (size_t)item * 9216;

  // step1: Qs = S3 * P  (96 x TW)
  {
    int nact = (TW == 32) ? 192 : 96;
    if (t < nact) {
      int r  = (TW == 32) ? (t >> 1) : t;
      int c0 = (TW == 32) ? (t & 1) * 16 : 0;
      const float* srow = S3 + r*96;
      f4 acc[4] = {f4zero(), f4zero(), f4zero(), f4zero()};
      #pragma unroll 4
      for (int k = 0; k < 96; ++k) {
        float a = srow[k];
        const float* pr = P + k*32 + c0;
        fma4(acc[0], a, ld4(pr));   fma4(acc[1], a, ld4(pr+4));
        fma4(acc[2], a, ld4(pr+8)); fma4(acc[3], a, ld4(pr+12));
      }
      #pragma unroll
      for (int u = 0; u < 4; ++u) st4(&Qs[r][c0 + u*4], acc[u]);
    }
  }
  __syncthreads();

  // step2: Gram = Qs^T Qs -> aug[:,0:TW];  identity -> aug[:,TW:2TW]
  {
    int nt4 = TW >> 2, nt = TW * nt4;
    if (t < nt) {
      int arow = t / nt4, b4 = (t % nt4) * 4;
      f4 acc = f4zero();
      #pragma unroll 4
      for (int k = 0; k < 96; ++k) fma4(acc, Qs[k][arow], ld4(&Qs[k][b4]));
      st4(&aug[arow][b4], acc);
    } else if (t < nt + TW) {
      int i = t - nt;
      for (int j = 0; j < TW; j += 4)
        st4(&aug[i][TW+j], make_float4(i==j?1.f:0.f, i==j+1?1.f:0.f,
                                       i==j+2?1.f:0.f, i==j+3?1.f:0.f));
    }
  }
  gauss_jordan(aug, colbuf, TW, 2*TW);      // K in aug[:,TW:2TW]

  // step3: K^T -> aug[:,0:TW]  (disjoint regions, no race)
  for (int e = t; e < TW*TW; e += 512) {
    int m = e / TW, c = e % TW;
    aug[c][m] = aug[m][TW + c];
  }
  __syncthreads();

  // step4: AKs = Qs * K  (dots vs K^T rows)
  {
    int nact = (TW == 32) ? 384 : 192;
    if (t < nact) {
      int i  = (TW == 32) ? (t >> 2) : (t >> 1);
      int c0 = ((TW == 32) ? (t & 3) : (t & 1)) * 8;
      float acc[8] = {0,0,0,0,0,0,0,0};
      for (int k4 = 0; k4 < TW; k4 += 4) {
        f4 qv = ld4(&Qs[i][k4]);
        #pragma unroll
        for (int b = 0; b < 8; ++b) acc[b] = dot4(qv, ld4(&aug[c0+b][k4]), acc[b]);
      }
      st4(&AKs[i][c0],   make_float4(acc[0],acc[1],acc[2],acc[3]));
      st4(&AKs[i][c0+4], make_float4(acc[4],acc[5],acc[6],acc[7]));
    }
  }
  __syncthreads();

  // step5: W = AKs * Qs^T ; write W1 (mode1) or Tg = W1 + W (mode2)
  if (t < 288) {
    int i0 = (t / 12) * 4, j0 = (t % 12) * 8;
    float acc[4][8];
    #pragma unroll
    for (int a = 0; a < 4; ++a)
      #pragma unroll
      for (int b = 0; b < 8; ++b) acc[a][b] = 0.f;
    for (int c4 = 0; c4 < TW; c4 += 4) {
      f4 av[4], bv[8];
      #pragma unroll
      for (int a = 0; a < 4; ++a) av[a] = ld4(&AKs[i0+a][c4]);
      #pragma unroll
      for (int b = 0; b < 8; ++b) bv[b] = ld4(&Qs[j0+b][c4]);
      #pragma unroll
      for (int a = 0; a < 4; ++a)
        #pragma unroll
        for (int b = 0; b < 8; ++b) acc[a][b] = dot4(av[a], bv[b], acc[a][b]);
    }
    #pragma unroll
    for (int a = 0; a < 4; ++a) {
      f4 w0 = make_float4(acc[a][0],acc[a][1],acc[a][2],acc[a][3]);
      f4 w1 = make_float4(acc[a][4],acc[a][5],acc[a][6],acc[a][7]);
      if (mode == 1) {
        st4(&W1[(i0+a)*96 + j0], w0); st4(&W1[(i0+a)*96 + j0 + 4], w1);
      } else {
        st4(&Tg[(i0+a)*96 + j0],     add4(w0, ld4(&W1[(i0+a)*96 + j0])));
        st4(&Tg[(i0+a)*96 + j0 + 4], add4(w1, ld4(&W1[(i0+a)*96 + j0 + 4])));
      }
    }
  }
}

// ---------------------------------------------------------------------------
// k4: out = T @ X.  grid (72, 8), block 256.
// ---------------------------------------------------------------------------
__global__ __launch_bounds__(256) void k4_out(
    const float* __restrict__ x, const float* __restrict__ Tgg,
    float* __restrict__ out) {
  __shared__ __align__(16) float Tt[96][100];
  int jb = blockIdx.x, item = blockIdx.y;
  const float* Tg = Tgg + (size_t)item * 9216;
  for (int e = TID * 4; e < 9216; e += 1024) {
    f4 v = ld4(&Tg[e]);
    int i = e / 96, k = e % 96;
    Tt[k][i] = v.x; Tt[k+1][i] = v.y; Tt[k+2][i] = v.z; Tt[k+3][i] = v.w;
  }
  __syncthreads();

  int jq = (TID % 32) * 4, ig = TID / 32;
  int i0 = ig * 12;
  int col = jb * 128 + jq;
  const float* X = x + (size_t)item * 96 * 9216;
  f4 acc[12];
  #pragma unroll
  for (int a = 0; a < 12; ++a) acc[a] = f4zero();

  for (int k = 0; k < 96; ++k) {
    f4 xv = ld4(&X[(size_t)k * 9216 + col]);
    f4 t0 = ld4(&Tt[k][i0]), t1 = ld4(&Tt[k][i0+4]), t2 = ld4(&Tt[k][i0+8]);
    fma4(acc[0], t0.x, xv); fma4(acc[1], t0.y, xv); fma4(acc[2], t0.z, xv); fma4(acc[3], t0.w, xv);
    fma4(acc[4], t1.x, xv); fma4(acc[5], t1.y, xv); fma4(acc[6], t1.z, xv); fma4(acc[7], t1.w, xv);
    fma4(acc[8], t2.x, xv); fma4(acc[9], t2.y, xv); fma4(acc[10], t2.z, xv); fma4(acc[11], t2.w, xv);
  }
  float* O = out + (size_t)item * 96 * 9216;
  #pragma unroll
  for (int a = 0; a < 12; ++a) st4(&O[(size_t)(i0 + a) * 9216 + col], acc[a]);
}

// ---------------------------------------------------------------------------
extern "C" void kernel_launch(void* const* d_in, const int* in_sizes, int n_in,
                              void* d_out, int out_size, void* d_ws, size_t ws_size,
                              hipStream_t stream) {
  (void)in_sizes; (void)n_in; (void)out_size;
  const float* x   = (const float*)d_in[0];
  const float* b01 = (const float*)d_in[2];
  const float* b02 = (const float*)d_in[4];
  float* out = (float*)d_out;
  float* ws  = (float*)d_ws;

  // extra region: M, C, S(=TMP), S2, S3, W1, Tg, P, Q, CP
  const size_t EXTRA = 73728ull*6 + 36864 + 24576*2 + 12288;   // 540,672 floats
  size_t need_big = ((size_t)64*8*9600 + EXTRA) * sizeof(float);
  int nch = (ws_size >= need_big) ? 64 : 32;
  int nsc = 9216 / nch / 48;

  float* Mb  = ws + (size_t)nch * 8 * 9600;
  float* Cb  = Mb  + 73728;
  float* Sb  = Cb  + 36864;    // S1 / S1' ; aliased as TMP
  float* S2b = Sb  + 73728;
  float* S3b = S2b + 73728;
  float* W1b = S3b + 73728;
  float* Tgb = W1b + 73728;
  float* Pb  = Tgb + 73728;
  float* Qb  = Pb  + 24576;
  float* CPb = Qb  + 24576;

  k1_partials<<<dim3(nch, 8), 512, 0, stream>>>(x, b01, b02, ws, nch, nsc);
  k2_reduce<<<dim3(75), 256, 0, stream>>>(ws, Mb, Cb, nch);

  // partition 1
  kw_phase<<<dim3(12,8),256,0,stream>>>(Mb, Mb, nullptr, Sb, SC27,
      nullptr,0,0,0, nullptr,0,0, 0);                                   // S1 = M^2*s
  kw_phase<<<dim3(13,8),256,0,stream>>>(Sb, Sb, nullptr, S2b, 1.f,
      Cb,4608,48,0, Qb,3072,32, 32);                                    // S2 ; Q = S1*C1
  kw_phase<<<dim3(13,8),256,0,stream>>>(S2b, S2b, nullptr, S3b, 1.f,
      Qb,3072,32,0, Pb,3072,32, 32);                                    // S3 ; P = S2*Q
  kf_proj<<<dim3(8),512,0,stream>>>(S3b, Pb, 32, W1b, Tgb, 1);          // W1

  // M2 construction
  kw_phase<<<dim3(13,8),256,0,stream>>>(W1b, Mb, Mb, Sb, 1.f,
      Cb+32,4608,48,1, CPb,1536,16, 16);                                // TMP = M - W1*M ; C2' = C2 - W1*C2
  kw_phase<<<dim3(12,8),256,0,stream>>>(Sb, W1b, Sb, Mb, 1.f,
      nullptr,0,0,0, nullptr,0,0, 0);                                   // M2 = TMP - TMP*W1

  // partition 2
  kw_phase<<<dim3(12,8),256,0,stream>>>(Mb, Mb, nullptr, Sb, SC27,
      nullptr,0,0,0, nullptr,0,0, 0);                                   // S1' = M2^2*s
  kw_phase<<<dim3(13,8),256,0,stream>>>(Sb, Sb, nullptr, S2b, 1.f,
      CPb,1536,16,0, Qb,3072,32, 16);                                   // S2' ; Q = S1'*C2'
  kw_phase<<<dim3(13,8),256,0,stream>>>(S2b, S2b, nullptr, S3b, 1.f,
      Qb,3072,32,0, Pb,3072,32, 16);                                    // S3' ; P = S2'*Q
  kf_proj<<<dim3(8),512,0,stream>>>(S3b, Pb, 16, W1b, Tgb, 2);          // Tg = W1 + W2

  k4_out<<<dim3(72, 8), 256, 0, stream>>>(x, Tgb, out);
}

// Round 7
// 242.914 us; speedup vs baseline: 1.0130x; 1.0130x over previous
//
#include <hip/hip_runtime.h>

// ---------------------------------------------------------------------------
// MRLR feature extractor, round 7: wide pipeline + wave-register Gauss-Jordan.
//   W1 = proj(M^14 C1): S1=M^2*2^-27, S2=S1^2, S3=S2^2, basis Q=S3*S2*S1*C1
//   TMP = M - W1 M; M2 = TMP - TMP W1; W2 = proj(M2^14 (C2 - W1 C2))
//   T = W1 + W2;  out = T X.
// k1: split-K partials (nch WGs/item, in-WG ksplit3 reduce)
// k2: reduce partials -> M (unpacked+mirrored) + C
// kw_phase x8: wide 96x96 GEMM phases (12-13 WGs/item) + optional thin part
// kf_proj x2: per-item Q=S3*P -> Gram -> wave-GJ -> AK -> W (1 WG/item)
// k4: out = T X
// ---------------------------------------------------------------------------

#define TID ((int)threadIdx.x)
typedef float4 f4;

#define SC27 (1.0f/134217728.0f)   // 2^-27

__device__ __forceinline__ f4 ld4(const float* p) { return *(const f4*)p; }
__device__ __forceinline__ void st4(float* p, f4 v) { *(f4*)p = v; }
__device__ __forceinline__ f4 f4zero() { return make_float4(0.f,0.f,0.f,0.f); }
__device__ __forceinline__ f4 add4(f4 a, f4 b){ return make_float4(a.x+b.x,a.y+b.y,a.z+b.z,a.w+b.w); }
__device__ __forceinline__ f4 sub4(f4 a, f4 b){ return make_float4(a.x-b.x,a.y-b.y,a.z-b.z,a.w-b.w); }
__device__ __forceinline__ f4 scl4(f4 a, float s){ return make_float4(a.x*s,a.y*s,a.z*s,a.w*s); }
__device__ __forceinline__ void fma4(f4& a, float s, f4 v) {
  a.x = fmaf(s,v.x,a.x); a.y = fmaf(s,v.y,a.y); a.z = fmaf(s,v.z,a.z); a.w = fmaf(s,v.w,a.w);
}
__device__ __forceinline__ float dot4(f4 a, f4 b, float acc) {
  acc = fmaf(a.x,b.x,acc); acc = fmaf(a.y,b.y,acc);
  acc = fmaf(a.z,b.z,acc); acc = fmaf(a.w,b.w,acc); return acc;
}
__device__ __forceinline__ void trimap(int t, int& ti, int& tj) {
  int rem = t; ti = 0;
  #pragma unroll
  for (int r = 0; r < 12; ++r) { int w = 12 - r; if (rem < w) { ti = r; break; } rem -= w; }
  tj = ti + rem;
}
__device__ __forceinline__ void init8(f4 acc[8][2]) {
  #pragma unroll
  for (int a = 0; a < 8; ++a) { acc[a][0] = f4zero(); acc[a][1] = f4zero(); }
}
__device__ __forceinline__ void tile8_step(f4 acc[8][2], const float* u, const float* v) {
  f4 u0 = ld4(u), u1 = ld4(u+4), v0 = ld4(v), v1 = ld4(v+4);
  float aa[8] = {u0.x,u0.y,u0.z,u0.w,u1.x,u1.y,u1.z,u1.w};
  #pragma unroll
  for (int a = 0; a < 8; ++a) { fma4(acc[a][0], aa[a], v0); fma4(acc[a][1], aa[a], v1); }
}

// ---------------------------------------------------------------------------
// k1: grid (nch, 8), block 512.  450 active: 3 k-parity x (78 tri-M + 72 C).
// ---------------------------------------------------------------------------
__global__ __launch_bounds__(512) void k1_partials(
    const float* __restrict__ x, const float* __restrict__ b01,
    const float* __restrict__ b02, float* __restrict__ part,
    int nch, int nsc) {
  __shared__ __align__(16) float Xst[48][100];
  __shared__ __align__(16) float Bs[48][52];
  __shared__ __align__(16) float red[9600];
  int kc = blockIdx.x, item = blockIdx.y;
  const float* X = x + (size_t)item * 96 * 9216;
  float* base = part + (size_t)(item * nch + kc) * 9600;

  int t = TID, kh = 0, tt = 0;
  const float* ap = nullptr; const float* bp = nullptr;
  float* op = nullptr; int os = 0; bool isM = false;
  bool active = (t < 450);
  if (active) {
    kh = t / 150; tt = t % 150;
    if (tt < 78) {
      int ti, tj; trimap(tt, ti, tj);
      ap = &Xst[0][ti*8]; bp = &Xst[0][tj*8];
      op = base + tt*64; os = 8; isM = true;
    } else {
      int u = tt - 78; int i0 = (u/6)*8, c0 = (u%6)*8;
      ap = &Xst[0][i0]; bp = &Bs[0][c0];
      op = base + 4992 + i0*48 + c0; os = 48;
    }
  }

  f4 acc[8][2]; init8(acc);

  for (int sc = 0; sc < nsc; ++sc) {
    int k0 = (kc * nsc + sc) * 48;
    __syncthreads();
    for (int e = TID; e < 1152; e += 512) {          // X slab transposed
      int i = e / 12, kq = (e % 12) * 4;
      f4 v = ld4(&X[(size_t)i * 9216 + k0 + kq]);
      Xst[kq][i] = v.x; Xst[kq+1][i] = v.y; Xst[kq+2][i] = v.z; Xst[kq+3][i] = v.w;
    }
    for (int e = TID; e < 384; e += 512) {           // B01
      int kk = e / 8, cq = (e % 8) * 4;
      st4(&Bs[kk][cq], ld4(&b01[(size_t)(k0 + kk) * 32 + cq]));
    }
    for (int e = TID; e < 192; e += 512) {           // B02
      int kk = e / 4, cq = (e % 4) * 4;
      st4(&Bs[kk][32+cq], ld4(&b02[(size_t)(k0 + kk) * 16 + cq]));
    }
    __syncthreads();
    if (active) {
      int asr = 100, bsr = isM ? 100 : 52;
      const float* ar = ap + kh * asr;
      const float* br = bp + kh * bsr;
      #pragma unroll 4
      for (int kk = kh; kk < 48; kk += 3) {
        tile8_step(acc, ar, br);
        ar += 3 * asr; br += 3 * bsr;
      }
    }
  }
  // 2-hop reduce: kh1 -> red -> kh0; kh2 -> red -> kh0; store.
  __syncthreads();
  if (active && kh == 1) {
    #pragma unroll
    for (int a = 0; a < 8; ++a) { st4(&red[tt*64+a*8], acc[a][0]); st4(&red[tt*64+a*8+4], acc[a][1]); }
  }
  __syncthreads();
  if (active && kh == 0) {
    #pragma unroll
    for (int a = 0; a < 8; ++a) {
      acc[a][0] = add4(acc[a][0], ld4(&red[tt*64+a*8]));
      acc[a][1] = add4(acc[a][1], ld4(&red[tt*64+a*8+4]));
    }
  }
  __syncthreads();
  if (active && kh == 2) {
    #pragma unroll
    for (int a = 0; a < 8; ++a) { st4(&red[tt*64+a*8], acc[a][0]); st4(&red[tt*64+a*8+4], acc[a][1]); }
  }
  __syncthreads();
  if (active && kh == 0) {
    #pragma unroll
    for (int a = 0; a < 8; ++a) {
      f4 s0 = add4(acc[a][0], ld4(&red[tt*64+a*8]));
      f4 s1 = add4(acc[a][1], ld4(&red[tt*64+a*8+4]));
      st4(op + a*os, s0); st4(op + a*os + 4, s1);
    }
  }
}

// ---------------------------------------------------------------------------
// k2: reduce nch partials -> M unpacked (mirrored) + C.  grid 75 x 256.
// ---------------------------------------------------------------------------
__global__ __launch_bounds__(256) void k2_reduce(
    const float* __restrict__ part, float* __restrict__ Mb,
    float* __restrict__ Cb, int nch) {
  int gid = blockIdx.x * 256 + TID;       // < 19200
  int item = gid / 2400, q4 = gid % 2400;
  int off = q4 * 4;
  const float* p = part + (size_t)item * nch * 9600 + off;
  f4 s = f4zero();
  #pragma unroll 8
  for (int c = 0; c < nch; ++c) s = add4(s, ld4(p + (size_t)c * 9600));
  if (off < 4992) {
    int tile = off >> 6, w = (off & 63) >> 2;
    int r = w >> 1, cq = (w & 1) * 4;
    int ti, tj; trimap(tile, ti, tj);
    int i = ti*8 + r, j = tj*8 + cq;
    float* Mi = Mb + (size_t)item * 9216;
    st4(&Mi[i*96 + j], s);
    Mi[(j+0)*96 + i] = s.x; Mi[(j+1)*96 + i] = s.y;
    Mi[(j+2)*96 + i] = s.z; Mi[(j+3)*96 + i] = s.w;
  } else {
    st4(&Cb[(size_t)item * 4608 + (off - 4992)], s);
  }
}

// ---------------------------------------------------------------------------
// kw_phase: wide GEMM phase.  grid (12 or 13, 8), block 256.
// ---------------------------------------------------------------------------
__global__ __launch_bounds__(256) void kw_phase(
    const float* __restrict__ Ag, const float* __restrict__ Bg,
    const float* __restrict__ Subg, float* __restrict__ Dg, float scale,
    const float* __restrict__ Tin, int ti_istr, int tis, int tsub,
    float* __restrict__ Tout, int to_istr, int tos, int TW) {
  int w = blockIdx.x, item = blockIdx.y;
  const float* A = Ag + (size_t)item * 9216;
  if (w < 12) {
    if (TID >= 192) return;
    const float* B = Bg + (size_t)item * 9216;
    float* D = Dg + (size_t)item * 9216;
    int r = w*8 + TID/24, jb = (TID%24)*4;
    const float* arow = A + r*96;
    f4 acc = f4zero();
    #pragma unroll 8
    for (int k = 0; k < 96; ++k) fma4(acc, arow[k], ld4(&B[k*96 + jb]));
    if (Subg) acc = sub4(ld4(&Subg[(size_t)item*9216 + r*96 + jb]), acc);
    else      acc = scl4(acc, scale);
    st4(&D[r*96 + jb], acc);
  } else {
    int nact = (TW == 32) ? 192 : 96;
    if (TID >= nact) return;
    int r  = (TW == 32) ? (TID >> 1) : TID;
    int c0 = (TW == 32) ? (TID & 1) * 16 : 0;
    const float* Ti = Tin + (size_t)item * ti_istr;
    float* To = Tout + (size_t)item * to_istr;
    const float* arow = A + r*96;
    f4 acc[4] = {f4zero(), f4zero(), f4zero(), f4zero()};
    #pragma unroll 4
    for (int k = 0; k < 96; ++k) {
      float a = arow[k];
      const float* tr = Ti + (size_t)k * tis + c0;
      fma4(acc[0], a, ld4(tr));   fma4(acc[1], a, ld4(tr+4));
      fma4(acc[2], a, ld4(tr+8)); fma4(acc[3], a, ld4(tr+12));
    }
    if (tsub) {
      const float* sr = Ti + (size_t)r * tis + c0;
      #pragma unroll
      for (int u = 0; u < 4; ++u) acc[u] = sub4(ld4(sr + u*4), acc[u]);
    }
    #pragma unroll
    for (int u = 0; u < 4; ++u) st4(&To[(size_t)r * tos + c0 + u*4], acc[u]);
  }
}

// ---------------------------------------------------------------------------
// Wave-register Gauss-Jordan: lane j < R owns column j of G (from aug left
// half); lane R <= j < 2R owns identity column j-R (register-initialized).
// Fully unrolled: all col[] indices static.  Zero barriers, zero LDS inside.
// Result: K = G^-1 columns stored to aug[:, R..2R).
// ---------------------------------------------------------------------------
template<int R>
__device__ void gj_wave(float (*aug)[64], int lane) {
  float col[R];
  if (lane < R) {
    #pragma unroll
    for (int i = 0; i < R; ++i) col[i] = aug[i][lane];
  } else {
    #pragma unroll
    for (int i = 0; i < R; ++i) col[i] = (i == lane - R) ? 1.f : 0.f;
  }
  #pragma unroll
  for (int c = 0; c < R; ++c) {
    float pc = __shfl(col[c], c);        // pivot a[c][c] (from lane c, reg c)
    float rp = 1.f / pc;
    bool isc = (lane == c);
    #pragma unroll
    for (int i = 0; i < R; ++i) {
      if (i == c) continue;
      float fi = __shfl(col[i], c) * rp; // a[i][c]/a[c][c], same in all lanes
      float v = fmaf(-fi, col[c], col[i]);
      col[i] = isc ? 0.f : v;            // eliminated column -> exact zero
    }
  }
  // normalize: row i of solution = K-col entries / diag a[i][i]
  #pragma unroll
  for (int i = 0; i < R; ++i) {
    float d = __shfl(col[i], i);         // diag from lane i, reg i
    col[i] = col[i] / d;
  }
  if (lane >= R) {
    #pragma unroll
    for (int i = 0; i < R; ++i) aug[i][lane] = col[i];
  }
}

// ---------------------------------------------------------------------------
// kf_proj<TW,MODE>: per-item fused Q=S3*P -> Gram -> wave-GJ -> AK -> W.
// grid(8) x 384.  MODE 1: W -> W1g.   MODE 2: Tg = W1g + W.
// ---------------------------------------------------------------------------
template<int TW, int MODE>
__global__ __launch_bounds__(384) void kf_proj(
    const float* __restrict__ S3g, const float* __restrict__ Pg,
    float* __restrict__ W1g, float* __restrict__ Tgg) {
  __shared__ __align__(16) float Qs[96][32];
  __shared__ __align__(16) float AKs[96][32];
  __shared__ __align__(16) float aug[32][64];

  int item = blockIdx.x, t = TID;
  const float* S3 = S3g + (size_t)item * 9216;
  const float* P  = Pg  + (size_t)item * 3072;
  float* W1 = W1g + (size_t)item * 9216;
  float* Tg = Tgg + (size_t)item * 9216;

  // step1: Qs = S3 * P  (96 x TW)
  {
    const int nact = (TW == 32) ? 192 : 96;
    if (t < nact) {
      int r  = (TW == 32) ? (t >> 1) : t;
      int c0 = (TW == 32) ? (t & 1) * 16 : 0;
      const float* srow = S3 + r*96;
      f4 acc[4] = {f4zero(), f4zero(), f4zero(), f4zero()};
      #pragma unroll 4
      for (int k = 0; k < 96; ++k) {
        float a = srow[k];
        const float* pr = P + k*32 + c0;
        fma4(acc[0], a, ld4(pr));   fma4(acc[1], a, ld4(pr+4));
        fma4(acc[2], a, ld4(pr+8)); fma4(acc[3], a, ld4(pr+12));
      }
      #pragma unroll
      for (int u = 0; u < 4; ++u) st4(&Qs[r][c0 + u*4], acc[u]);
    }
  }
  __syncthreads();

  // step2: Gram = Qs^T Qs -> aug[:,0:TW]
  {
    const int nt4 = TW >> 2;
    if (t < TW * nt4) {
      int arow = t / nt4, b4 = (t % nt4) * 4;
      f4 acc = f4zero();
      #pragma unroll 4
      for (int k = 0; k < 96; ++k) fma4(acc, Qs[k][arow], ld4(&Qs[k][b4]));
      st4(&aug[arow][b4], acc);
    }
  }
  __syncthreads();

  // step3: wave-GJ on wave 0 -> K in aug[:,TW:2TW]
  if (t < 2*TW) gj_wave<TW>(aug, t);
  __syncthreads();

  // step3b: K^T -> aug[:,0:TW]
  for (int e = t; e < TW*TW; e += 384) {
    int m = e / TW, c = e % TW;
    aug[c][m] = aug[m][TW + c];
  }
  __syncthreads();

  // step4: AKs = Qs * K  (dots vs K^T rows)
  {
    const int nact = (TW == 32) ? 384 : 192;
    if (t < nact) {
      int i  = (TW == 32) ? (t >> 2) : (t >> 1);
      int c0 = ((TW == 32) ? (t & 3) : (t & 1)) * 8;
      float acc[8] = {0,0,0,0,0,0,0,0};
      #pragma unroll
      for (int k4 = 0; k4 < TW; k4 += 4) {
        f4 qv = ld4(&Qs[i][k4]);
        #pragma unroll
        for (int b = 0; b < 8; ++b) acc[b] = dot4(qv, ld4(&aug[c0+b][k4]), acc[b]);
      }
      st4(&AKs[i][c0],   make_float4(acc[0],acc[1],acc[2],acc[3]));
      st4(&AKs[i][c0+4], make_float4(acc[4],acc[5],acc[6],acc[7]));
    }
  }
  __syncthreads();

  // step5: W = AKs * Qs^T ; write W1 (MODE 1) or Tg = W1 + W (MODE 2)
  if (t < 288) {
    int i0 = (t / 12) * 4, j0 = (t % 12) * 8;
    float acc[4][8];
    #pragma unroll
    for (int a = 0; a < 4; ++a)
      #pragma unroll
      for (int b = 0; b < 8; ++b) acc[a][b] = 0.f;
    #pragma unroll
    for (int c4 = 0; c4 < TW; c4 += 4) {
      f4 av[4], bv[8];
      #pragma unroll
      for (int a = 0; a < 4; ++a) av[a] = ld4(&AKs[i0+a][c4]);
      #pragma unroll
      for (int b = 0; b < 8; ++b) bv[b] = ld4(&Qs[j0+b][c4]);
      #pragma unroll
      for (int a = 0; a < 4; ++a)
        #pragma unroll
        for (int b = 0; b < 8; ++b) acc[a][b] = dot4(av[a], bv[b], acc[a][b]);
    }
    #pragma unroll
    for (int a = 0; a < 4; ++a) {
      f4 w0 = make_float4(acc[a][0],acc[a][1],acc[a][2],acc[a][3]);
      f4 w1 = make_float4(acc[a][4],acc[a][5],acc[a][6],acc[a][7]);
      if (MODE == 1) {
        st4(&W1[(i0+a)*96 + j0], w0); st4(&W1[(i0+a)*96 + j0 + 4], w1);
      } else {
        st4(&Tg[(i0+a)*96 + j0],     add4(w0, ld4(&W1[(i0+a)*96 + j0])));
        st4(&Tg[(i0+a)*96 + j0 + 4], add4(w1, ld4(&W1[(i0+a)*96 + j0 + 4])));
      }
    }
  }
}

// ---------------------------------------------------------------------------
// k4: out = T @ X.  grid (72, 8), block 256.
// ---------------------------------------------------------------------------
__global__ __launch_bounds__(256) void k4_out(
    const float* __restrict__ x, const float* __restrict__ Tgg,
    float* __restrict__ out) {
  __shared__ __align__(16) float Tt[96][100];
  int jb = blockIdx.x, item = blockIdx.y;
  const float* Tg = Tgg + (size_t)item * 9216;
  for (int e = TID * 4; e < 9216; e += 1024) {
    f4 v = ld4(&Tg[e]);
    int i = e / 96, k = e % 96;
    Tt[k][i] = v.x; Tt[k+1][i] = v.y; Tt[k+2][i] = v.z; Tt[k+3][i] = v.w;
  }
  __syncthreads();

  int jq = (TID % 32) * 4, ig = TID / 32;
  int i0 = ig * 12;
  int col = jb * 128 + jq;
  const float* X = x + (size_t)item * 96 * 9216;
  f4 acc[12];
  #pragma unroll
  for (int a = 0; a < 12; ++a) acc[a] = f4zero();

  for (int k = 0; k < 96; ++k) {
    f4 xv = ld4(&X[(size_t)k * 9216 + col]);
    f4 t0 = ld4(&Tt[k][i0]), t1 = ld4(&Tt[k][i0+4]), t2 = ld4(&Tt[k][i0+8]);
    fma4(acc[0], t0.x, xv); fma4(acc[1], t0.y, xv); fma4(acc[2], t0.z, xv); fma4(acc[3], t0.w, xv);
    fma4(acc[4], t1.x, xv); fma4(acc[5], t1.y, xv); fma4(acc[6], t1.z, xv); fma4(acc[7], t1.w, xv);
    fma4(acc[8], t2.x, xv); fma4(acc[9], t2.y, xv); fma4(acc[10], t2.z, xv); fma4(acc[11], t2.w, xv);
  }
  float* O = out + (size_t)item * 96 * 9216;
  #pragma unroll
  for (int a = 0; a < 12; ++a) st4(&O[(size_t)(i0 + a) * 9216 + col], acc[a]);
}

// ---------------------------------------------------------------------------
extern "C" void kernel_launch(void* const* d_in, const int* in_sizes, int n_in,
                              void* d_out, int out_size, void* d_ws, size_t ws_size,
                              hipStream_t stream) {
  (void)in_sizes; (void)n_in; (void)out_size;
  const float* x   = (const float*)d_in[0];
  const float* b01 = (const float*)d_in[2];
  const float* b02 = (const float*)d_in[4];
  float* out = (float*)d_out;
  float* ws  = (float*)d_ws;

  const size_t EXTRA = 73728ull*6 + 36864 + 24576*2 + 12288;   // 540,672 floats
  size_t need_big = ((size_t)64*8*9600 + EXTRA) * sizeof(float);
  int nch = (ws_size >= need_big) ? 64 : 32;
  int nsc = 9216 / nch / 48;

  float* Mb  = ws + (size_t)nch * 8 * 9600;
  float* Cb  = Mb  + 73728;
  float* Sb  = Cb  + 36864;    // S1 / S1' ; aliased as TMP
  float* S2b = Sb  + 73728;
  float* S3b = S2b + 73728;
  float* W1b = S3b + 73728;
  float* Tgb = W1b + 73728;
  float* Pb  = Tgb + 73728;
  float* Qb  = Pb  + 24576;
  float* CPb = Qb  + 24576;

  k1_partials<<<dim3(nch, 8), 512, 0, stream>>>(x, b01, b02, ws, nch, nsc);
  k2_reduce<<<dim3(75), 256, 0, stream>>>(ws, Mb, Cb, nch);

  // partition 1
  kw_phase<<<dim3(12,8),256,0,stream>>>(Mb, Mb, nullptr, Sb, SC27,
      nullptr,0,0,0, nullptr,0,0, 0);                                   // S1 = M^2*s
  kw_phase<<<dim3(13,8),256,0,stream>>>(Sb, Sb, nullptr, S2b, 1.f,
      Cb,4608,48,0, Qb,3072,32, 32);                                    // S2 ; Q = S1*C1
  kw_phase<<<dim3(13,8),256,0,stream>>>(S2b, S2b, nullptr, S3b, 1.f,
      Qb,3072,32,0, Pb,3072,32, 32);                                    // S3 ; P = S2*Q
  kf_proj<32,1><<<dim3(8),384,0,stream>>>(S3b, Pb, W1b, Tgb);           // W1

  // M2 construction
  kw_phase<<<dim3(13,8),256,0,stream>>>(W1b, Mb, Mb, Sb, 1.f,
      Cb+32,4608,48,1, CPb,1536,16, 16);                                // TMP = M - W1*M ; C2' = C2 - W1*C2
  kw_phase<<<dim3(12,8),256,0,stream>>>(Sb, W1b, Sb, Mb, 1.f,
      nullptr,0,0,0, nullptr,0,0, 0);                                   // M2 = TMP - TMP*W1

  // partition 2
  kw_phase<<<dim3(12,8),256,0,stream>>>(Mb, Mb, nullptr, Sb, SC27,
      nullptr,0,0,0, nullptr,0,0, 0);                                   // S1' = M2^2*s
  kw_phase<<<dim3(13,8),256,0,stream>>>(Sb, Sb, nullptr, S2b, 1.f,
      CPb,1536,16,0, Qb,3072,32, 16);                                   // S2' ; Q = S1'*C2'
  kw_phase<<<dim3(13,8),256,0,stream>>>(S2b, S2b, nullptr, S3b, 1.f,
      Qb,3072,32,0, Pb,3072,32, 16);                                    // S3' ; P = S2'*Q
  kf_proj<16,2><<<dim3(8),384,0,stream>>>(S3b, Pb, W1b, Tgb);           // Tg = W1 + W2

  k4_out<<<dim3(72, 8), 256, 0, stream>>>(x, Tgb, out);
}

// Round 8
// 238.761 us; speedup vs baseline: 1.0307x; 1.0174x over previous
//
#include <hip/hip_runtime.h>

// ---------------------------------------------------------------------------
// MRLR feature extractor, round 8: all matrix-sized traffic in wide kernels;
// per-item serial kernel touches only Q (12 KB) in one parallel load.
//   W1 = proj(M^14 C1): S1=M^2*2^-27, S2=S1^2, S3=S2^2, Q = S3*S2*S1*C1
//   TMP = M - W1 M; M2 = TMP - TMP W1; W2 = proj(M2^14 (C2 - W1 C2))
//   T = W1 + W2;  out = T X.
// k1 partials -> k2 reduce -> kw_phase x8 (wide) -> kq_thin x2 (wide)
// -> kf_small x2 (Gram/GJ/AK, tiny) -> kw_W x2 (wide) -> k4.
// ---------------------------------------------------------------------------

#define TID ((int)threadIdx.x)
typedef float4 f4;

#define SC27 (1.0f/134217728.0f)   // 2^-27

__device__ __forceinline__ f4 ld4(const float* p) { return *(const f4*)p; }
__device__ __forceinline__ void st4(float* p, f4 v) { *(f4*)p = v; }
__device__ __forceinline__ f4 f4zero() { return make_float4(0.f,0.f,0.f,0.f); }
__device__ __forceinline__ f4 add4(f4 a, f4 b){ return make_float4(a.x+b.x,a.y+b.y,a.z+b.z,a.w+b.w); }
__device__ __forceinline__ f4 sub4(f4 a, f4 b){ return make_float4(a.x-b.x,a.y-b.y,a.z-b.z,a.w-b.w); }
__device__ __forceinline__ f4 scl4(f4 a, float s){ return make_float4(a.x*s,a.y*s,a.z*s,a.w*s); }
__device__ __forceinline__ void fma4(f4& a, float s, f4 v) {
  a.x = fmaf(s,v.x,a.x); a.y = fmaf(s,v.y,a.y); a.z = fmaf(s,v.z,a.z); a.w = fmaf(s,v.w,a.w);
}
__device__ __forceinline__ float dot4(f4 a, f4 b, float acc) {
  acc = fmaf(a.x,b.x,acc); acc = fmaf(a.y,b.y,acc);
  acc = fmaf(a.z,b.z,acc); acc = fmaf(a.w,b.w,acc); return acc;
}
__device__ __forceinline__ void trimap(int t, int& ti, int& tj) {
  int rem = t; ti = 0;
  #pragma unroll
  for (int r = 0; r < 12; ++r) { int w = 12 - r; if (rem < w) { ti = r; break; } rem -= w; }
  tj = ti + rem;
}
__device__ __forceinline__ void init8(f4 acc[8][2]) {
  #pragma unroll
  for (int a = 0; a < 8; ++a) { acc[a][0] = f4zero(); acc[a][1] = f4zero(); }
}
__device__ __forceinline__ void tile8_step(f4 acc[8][2], const float* u, const float* v) {
  f4 u0 = ld4(u), u1 = ld4(u+4), v0 = ld4(v), v1 = ld4(v+4);
  float aa[8] = {u0.x,u0.y,u0.z,u0.w,u1.x,u1.y,u1.z,u1.w};
  #pragma unroll
  for (int a = 0; a < 8; ++a) { fma4(acc[a][0], aa[a], v0); fma4(acc[a][1], aa[a], v1); }
}

// ---------------------------------------------------------------------------
// k1: grid (nch, 8), block 512.  450 active: 3 k-parity x (78 tri-M + 72 C).
// ---------------------------------------------------------------------------
__global__ __launch_bounds__(512) void k1_partials(
    const float* __restrict__ x, const float* __restrict__ b01,
    const float* __restrict__ b02, float* __restrict__ part,
    int nch, int nsc) {
  __shared__ __align__(16) float Xst[48][100];
  __shared__ __align__(16) float Bs[48][52];
  __shared__ __align__(16) float red[9600];
  int kc = blockIdx.x, item = blockIdx.y;
  const float* X = x + (size_t)item * 96 * 9216;
  float* base = part + (size_t)(item * nch + kc) * 9600;

  int t = TID, kh = 0, tt = 0;
  const float* ap = nullptr; const float* bp = nullptr;
  float* op = nullptr; int os = 0; bool isM = false;
  bool active = (t < 450);
  if (active) {
    kh = t / 150; tt = t % 150;
    if (tt < 78) {
      int ti, tj; trimap(tt, ti, tj);
      ap = &Xst[0][ti*8]; bp = &Xst[0][tj*8];
      op = base + tt*64; os = 8; isM = true;
    } else {
      int u = tt - 78; int i0 = (u/6)*8, c0 = (u%6)*8;
      ap = &Xst[0][i0]; bp = &Bs[0][c0];
      op = base + 4992 + i0*48 + c0; os = 48;
    }
  }

  f4 acc[8][2]; init8(acc);

  for (int sc = 0; sc < nsc; ++sc) {
    int k0 = (kc * nsc + sc) * 48;
    __syncthreads();
    for (int e = TID; e < 1152; e += 512) {          // X slab transposed
      int i = e / 12, kq = (e % 12) * 4;
      f4 v = ld4(&X[(size_t)i * 9216 + k0 + kq]);
      Xst[kq][i] = v.x; Xst[kq+1][i] = v.y; Xst[kq+2][i] = v.z; Xst[kq+3][i] = v.w;
    }
    for (int e = TID; e < 384; e += 512) {           // B01
      int kk = e / 8, cq = (e % 8) * 4;
      st4(&Bs[kk][cq], ld4(&b01[(size_t)(k0 + kk) * 32 + cq]));
    }
    for (int e = TID; e < 192; e += 512) {           // B02
      int kk = e / 4, cq = (e % 4) * 4;
      st4(&Bs[kk][32+cq], ld4(&b02[(size_t)(k0 + kk) * 16 + cq]));
    }
    __syncthreads();
    if (active) {
      int asr = 100, bsr = isM ? 100 : 52;
      const float* ar = ap + kh * asr;
      const float* br = bp + kh * bsr;
      #pragma unroll 4
      for (int kk = kh; kk < 48; kk += 3) {
        tile8_step(acc, ar, br);
        ar += 3 * asr; br += 3 * bsr;
      }
    }
  }
  __syncthreads();
  if (active && kh == 1) {
    #pragma unroll
    for (int a = 0; a < 8; ++a) { st4(&red[tt*64+a*8], acc[a][0]); st4(&red[tt*64+a*8+4], acc[a][1]); }
  }
  __syncthreads();
  if (active && kh == 0) {
    #pragma unroll
    for (int a = 0; a < 8; ++a) {
      acc[a][0] = add4(acc[a][0], ld4(&red[tt*64+a*8]));
      acc[a][1] = add4(acc[a][1], ld4(&red[tt*64+a*8+4]));
    }
  }
  __syncthreads();
  if (active && kh == 2) {
    #pragma unroll
    for (int a = 0; a < 8; ++a) { st4(&red[tt*64+a*8], acc[a][0]); st4(&red[tt*64+a*8+4], acc[a][1]); }
  }
  __syncthreads();
  if (active && kh == 0) {
    #pragma unroll
    for (int a = 0; a < 8; ++a) {
      f4 s0 = add4(acc[a][0], ld4(&red[tt*64+a*8]));
      f4 s1 = add4(acc[a][1], ld4(&red[tt*64+a*8+4]));
      st4(op + a*os, s0); st4(op + a*os + 4, s1);
    }
  }
}

// ---------------------------------------------------------------------------
// k2: reduce nch partials -> M unpacked (mirrored) + C.  grid 75 x 256.
// ---------------------------------------------------------------------------
__global__ __launch_bounds__(256) void k2_reduce(
    const float* __restrict__ part, float* __restrict__ Mb,
    float* __restrict__ Cb, int nch) {
  int gid = blockIdx.x * 256 + TID;       // < 19200
  int item = gid / 2400, q4 = gid % 2400;
  int off = q4 * 4;
  const float* p = part + (size_t)item * nch * 9600 + off;
  f4 s = f4zero();
  #pragma unroll 8
  for (int c = 0; c < nch; ++c) s = add4(s, ld4(p + (size_t)c * 9600));
  if (off < 4992) {
    int tile = off >> 6, w = (off & 63) >> 2;
    int r = w >> 1, cq = (w & 1) * 4;
    int ti, tj; trimap(tile, ti, tj);
    int i = ti*8 + r, j = tj*8 + cq;
    float* Mi = Mb + (size_t)item * 9216;
    st4(&Mi[i*96 + j], s);
    Mi[(j+0)*96 + i] = s.x; Mi[(j+1)*96 + i] = s.y;
    Mi[(j+2)*96 + i] = s.z; Mi[(j+3)*96 + i] = s.w;
  } else {
    st4(&Cb[(size_t)item * 4608 + (off - 4992)], s);
  }
}

// ---------------------------------------------------------------------------
// kw_phase: wide GEMM phase.  grid (12 or 13, 8), block 256.
// ---------------------------------------------------------------------------
__global__ __launch_bounds__(256) void kw_phase(
    const float* __restrict__ Ag, const float* __restrict__ Bg,
    const float* __restrict__ Subg, float* __restrict__ Dg, float scale,
    const float* __restrict__ Tin, int ti_istr, int tis, int tsub,
    float* __restrict__ Tout, int to_istr, int tos, int TW) {
  int w = blockIdx.x, item = blockIdx.y;
  const float* A = Ag + (size_t)item * 9216;
  if (w < 12) {
    if (TID >= 192) return;
    const float* B = Bg + (size_t)item * 9216;
    float* D = Dg + (size_t)item * 9216;
    int r = w*8 + TID/24, jb = (TID%24)*4;
    const float* arow = A + r*96;
    f4 acc = f4zero();
    #pragma unroll 8
    for (int k = 0; k < 96; ++k) fma4(acc, arow[k], ld4(&B[k*96 + jb]));
    if (Subg) acc = sub4(ld4(&Subg[(size_t)item*9216 + r*96 + jb]), acc);
    else      acc = scl4(acc, scale);
    st4(&D[r*96 + jb], acc);
  } else {
    int nact = (TW == 32) ? 192 : 96;
    if (TID >= nact) return;
    int r  = (TW == 32) ? (TID >> 1) : TID;
    int c0 = (TW == 32) ? (TID & 1) * 16 : 0;
    const float* Ti = Tin + (size_t)item * ti_istr;
    float* To = Tout + (size_t)item * to_istr;
    const float* arow = A + r*96;
    f4 acc[4] = {f4zero(), f4zero(), f4zero(), f4zero()};
    #pragma unroll 4
    for (int k = 0; k < 96; ++k) {
      float a = arow[k];
      const float* tr = Ti + (size_t)k * tis + c0;
      fma4(acc[0], a, ld4(tr));   fma4(acc[1], a, ld4(tr+4));
      fma4(acc[2], a, ld4(tr+8)); fma4(acc[3], a, ld4(tr+12));
    }
    if (tsub) {
      const float* sr = Ti + (size_t)r * tis + c0;
      #pragma unroll
      for (int u = 0; u < 4; ++u) acc[u] = sub4(ld4(sr + u*4), acc[u]);
    }
    #pragma unroll
    for (int u = 0; u < 4; ++u) st4(&To[(size_t)r * tos + c0 + u*4], acc[u]);
  }
}

// ---------------------------------------------------------------------------
// kq_thin: Q = S3 * P (96 x TW), wide.  grid (3, 8), block 256.
// ---------------------------------------------------------------------------
__global__ __launch_bounds__(256) void kq_thin(
    const float* __restrict__ S3g, const float* __restrict__ Pg,
    float* __restrict__ Qg, int TW) {
  int w = blockIdx.x, item = blockIdx.y;
  int ng = TW >> 2;
  if (TID >= 32*ng) return;
  const float* S3 = S3g + (size_t)item * 9216;
  const float* P  = Pg  + (size_t)item * 3072;
  float* Qo = Qg + (size_t)item * 3072;
  int r = w*32 + TID/ng, c0 = (TID%ng)*4;
  const float* srow = S3 + r*96;
  f4 acc = f4zero();
  #pragma unroll 4
  for (int k = 0; k < 96; ++k) fma4(acc, srow[k], ld4(&P[k*32 + c0]));
  st4(&Qo[r*32 + c0], acc);
}

// ---------------------------------------------------------------------------
// Wave-register Gauss-Jordan (verified round 7): lane j < R owns column j of
// G; lanes [R,2R) own identity columns.  Zero barriers / LDS inside.
// ---------------------------------------------------------------------------
template<int R>
__device__ void gj_wave(float (*aug)[64], int lane) {
  float col[R];
  if (lane < R) {
    #pragma unroll
    for (int i = 0; i < R; ++i) col[i] = aug[i][lane];
  } else {
    #pragma unroll
    for (int i = 0; i < R; ++i) col[i] = (i == lane - R) ? 1.f : 0.f;
  }
  #pragma unroll
  for (int c = 0; c < R; ++c) {
    float pc = __shfl(col[c], c);
    float rp = 1.f / pc;
    bool isc = (lane == c);
    #pragma unroll
    for (int i = 0; i < R; ++i) {
      if (i == c) continue;
      float fi = __shfl(col[i], c) * rp;
      float v = fmaf(-fi, col[c], col[i]);
      col[i] = isc ? 0.f : v;
    }
  }
  #pragma unroll
  for (int i = 0; i < R; ++i) {
    float d = __shfl(col[i], i);
    col[i] = col[i] / d;
  }
  if (lane >= R) {
    #pragma unroll
    for (int i = 0; i < R; ++i) aug[i][lane] = col[i];
  }
}

// ---------------------------------------------------------------------------
// kf_small<TW>: Gram -> wave-GJ -> AK, touching only Q (12 KB) + AK (12 KB).
// grid (8), block 256.
// ---------------------------------------------------------------------------
template<int TW>
__global__ __launch_bounds__(256) void kf_small(
    const float* __restrict__ Qg, float* __restrict__ AKg) {
  __shared__ __align__(16) float Qs[96][32];
  __shared__ __align__(16) float aug[32][64];
  int item = blockIdx.x, t = TID;
  const float* Q = Qg + (size_t)item * 3072;
  float* AK = AKg + (size_t)item * 3072;

  // load Q (one parallel round: 768 f4 over 256 threads)
  for (int e = t*4; e < 3072; e += 1024) st4(&Qs[e>>5][e&31], ld4(&Q[e]));
  __syncthreads();

  // Gram = Qs^T Qs -> aug[:,0:TW]
  {
    const int ng = TW >> 2;
    if (t < TW*ng) {
      int ar = t/ng, b4 = (t%ng)*4;
      f4 acc = f4zero();
      #pragma unroll 4
      for (int k = 0; k < 96; ++k) fma4(acc, Qs[k][ar], ld4(&Qs[k][b4]));
      st4(&aug[ar][b4], acc);
    }
  }
  __syncthreads();

  if (t < 2*TW) gj_wave<TW>(aug, t);
  __syncthreads();

  // K^T -> aug[:,0:TW]
  for (int e = t; e < TW*TW; e += 256) { int m = e/TW, c = e%TW; aug[c][m] = aug[m][TW+c]; }
  __syncthreads();

  // AK = Qs * K  (dot vs K^T rows) -> global
  {
    const int ng = TW >> 2;
    for (int e = t; e < 96*ng; e += 256) {
      int i = e/ng, c0 = (e%ng)*4;
      float a0=0.f, a1=0.f, a2=0.f, a3=0.f;
      #pragma unroll
      for (int m4 = 0; m4 < TW; m4 += 4) {
        f4 qv = ld4(&Qs[i][m4]);
        a0 = dot4(qv, ld4(&aug[c0+0][m4]), a0);
        a1 = dot4(qv, ld4(&aug[c0+1][m4]), a1);
        a2 = dot4(qv, ld4(&aug[c0+2][m4]), a2);
        a3 = dot4(qv, ld4(&aug[c0+3][m4]), a3);
      }
      st4(&AK[i*32 + c0], make_float4(a0,a1,a2,a3));
    }
  }
}

// ---------------------------------------------------------------------------
// kw_W: W = AK * Q^T (96x96) wide; D = [Add +] AK Q^T.  grid (12, 8) x 256.
// ---------------------------------------------------------------------------
__global__ __launch_bounds__(256) void kw_W(
    const float* __restrict__ AKg, const float* __restrict__ Qg,
    const float* __restrict__ Addg, float* __restrict__ Dg, int TW) {
  int w = blockIdx.x, item = blockIdx.y;
  if (TID >= 192) return;
  const float* AK = AKg + (size_t)item * 3072;
  const float* Q  = Qg  + (size_t)item * 3072;
  int r = w*8 + TID/24, jb = (TID%24)*4;
  const float* arow = AK + r*32;
  f4 acc = f4zero();
  #pragma unroll
  for (int c4 = 0; c4 < TW; c4 += 4) {
    f4 av = ld4(&arow[c4]);
    acc.x = dot4(av, ld4(&Q[(jb+0)*32 + c4]), acc.x);
    acc.y = dot4(av, ld4(&Q[(jb+1)*32 + c4]), acc.y);
    acc.z = dot4(av, ld4(&Q[(jb+2)*32 + c4]), acc.z);
    acc.w = dot4(av, ld4(&Q[(jb+3)*32 + c4]), acc.w);
  }
  if (Addg) acc = add4(acc, ld4(&Addg[(size_t)item*9216 + r*96 + jb]));
  st4(&Dg[(size_t)item*9216 + r*96 + jb], acc);
}

// ---------------------------------------------------------------------------
// k4: out = T @ X.  grid (72, 8), block 256.
// ---------------------------------------------------------------------------
__global__ __launch_bounds__(256) void k4_out(
    const float* __restrict__ x, const float* __restrict__ Tgg,
    float* __restrict__ out) {
  __shared__ __align__(16) float Tt[96][100];
  int jb = blockIdx.x, item = blockIdx.y;
  const float* Tg = Tgg + (size_t)item * 9216;
  for (int e = TID * 4; e < 9216; e += 1024) {
    f4 v = ld4(&Tg[e]);
    int i = e / 96, k = e % 96;
    Tt[k][i] = v.x; Tt[k+1][i] = v.y; Tt[k+2][i] = v.z; Tt[k+3][i] = v.w;
  }
  __syncthreads();

  int jq = (TID % 32) * 4, ig = TID / 32;
  int i0 = ig * 12;
  int col = jb * 128 + jq;
  const float* X = x + (size_t)item * 96 * 9216;
  f4 acc[12];
  #pragma unroll
  for (int a = 0; a < 12; ++a) acc[a] = f4zero();

  for (int k = 0; k < 96; ++k) {
    f4 xv = ld4(&X[(size_t)k * 9216 + col]);
    f4 t0 = ld4(&Tt[k][i0]), t1 = ld4(&Tt[k][i0+4]), t2 = ld4(&Tt[k][i0+8]);
    fma4(acc[0], t0.x, xv); fma4(acc[1], t0.y, xv); fma4(acc[2], t0.z, xv); fma4(acc[3], t0.w, xv);
    fma4(acc[4], t1.x, xv); fma4(acc[5], t1.y, xv); fma4(acc[6], t1.z, xv); fma4(acc[7], t1.w, xv);
    fma4(acc[8], t2.x, xv); fma4(acc[9], t2.y, xv); fma4(acc[10], t2.z, xv); fma4(acc[11], t2.w, xv);
  }
  float* O = out + (size_t)item * 96 * 9216;
  #pragma unroll
  for (int a = 0; a < 12; ++a) st4(&O[(size_t)(i0 + a) * 9216 + col], acc[a]);
}

// ---------------------------------------------------------------------------
extern "C" void kernel_launch(void* const* d_in, const int* in_sizes, int n_in,
                              void* d_out, int out_size, void* d_ws, size_t ws_size,
                              hipStream_t stream) {
  (void)in_sizes; (void)n_in; (void)out_size;
  const float* x   = (const float*)d_in[0];
  const float* b01 = (const float*)d_in[2];
  const float* b02 = (const float*)d_in[4];
  float* out = (float*)d_out;
  float* ws  = (float*)d_ws;

  const size_t EXTRA = 73728ull*6 + 36864 + 24576*3 + 12288;   // + AK buffer
  size_t need_big = ((size_t)64*8*9600 + EXTRA) * sizeof(float);
  int nch = (ws_size >= need_big) ? 64 : 32;
  int nsc = 9216 / nch / 48;

  float* Mb  = ws + (size_t)nch * 8 * 9600;
  float* Cb  = Mb  + 73728;
  float* Sb  = Cb  + 36864;    // S1 / S1' ; aliased as TMP
  float* S2b = Sb  + 73728;
  float* S3b = S2b + 73728;
  float* W1b = S3b + 73728;
  float* Tgb = W1b + 73728;
  float* Pb  = Tgb + 73728;
  float* Qb  = Pb  + 24576;
  float* AKb = Qb  + 24576;
  float* CPb = AKb + 24576;

  k1_partials<<<dim3(nch, 8), 512, 0, stream>>>(x, b01, b02, ws, nch, nsc);
  k2_reduce<<<dim3(75), 256, 0, stream>>>(ws, Mb, Cb, nch);

  // partition 1
  kw_phase<<<dim3(12,8),256,0,stream>>>(Mb, Mb, nullptr, Sb, SC27,
      nullptr,0,0,0, nullptr,0,0, 0);                                   // S1 = M^2*s
  kw_phase<<<dim3(13,8),256,0,stream>>>(Sb, Sb, nullptr, S2b, 1.f,
      Cb,4608,48,0, Qb,3072,32, 32);                                    // S2 ; Y = S1*C1 -> Qb
  kw_phase<<<dim3(13,8),256,0,stream>>>(S2b, S2b, nullptr, S3b, 1.f,
      Qb,3072,32,0, Pb,3072,32, 32);                                    // S3 ; P = S2*Y
  kq_thin<<<dim3(3,8),256,0,stream>>>(S3b, Pb, Qb, 32);                 // Q = S3*P
  kf_small<32><<<dim3(8),256,0,stream>>>(Qb, AKb);                      // Gram/GJ/AK
  kw_W<<<dim3(12,8),256,0,stream>>>(AKb, Qb, nullptr, W1b, 32);         // W1 = AK Q^T

  // M2 construction
  kw_phase<<<dim3(13,8),256,0,stream>>>(W1b, Mb, Mb, Sb, 1.f,
      Cb+32,4608,48,1, CPb,1536,16, 16);                                // TMP = M - W1*M ; C2'
  kw_phase<<<dim3(12,8),256,0,stream>>>(Sb, W1b, Sb, Mb, 1.f,
      nullptr,0,0,0, nullptr,0,0, 0);                                   // M2 = TMP - TMP*W1

  // partition 2
  kw_phase<<<dim3(12,8),256,0,stream>>>(Mb, Mb, nullptr, Sb, SC27,
      nullptr,0,0,0, nullptr,0,0, 0);                                   // S1' = M2^2*s
  kw_phase<<<dim3(13,8),256,0,stream>>>(Sb, Sb, nullptr, S2b, 1.f,
      CPb,1536,16,0, Qb,3072,32, 16);                                   // S2' ; Y = S1'*C2'
  kw_phase<<<dim3(13,8),256,0,stream>>>(S2b, S2b, nullptr, S3b, 1.f,
      Qb,3072,32,0, Pb,3072,32, 16);                                    // S3' ; P = S2'*Y
  kq_thin<<<dim3(3,8),256,0,stream>>>(S3b, Pb, Qb, 16);                 // Q = S3'*P
  kf_small<16><<<dim3(8),256,0,stream>>>(Qb, AKb);                      // Gram/GJ/AK
  kw_W<<<dim3(12,8),256,0,stream>>>(AKb, Qb, W1b, Tgb, 16);             // Tg = W1 + AK Q^T

  k4_out<<<dim3(72, 8), 256, 0, stream>>>(x, Tgb, out);
}

// Round 9
// 236.838 us; speedup vs baseline: 1.0390x; 1.0081x over previous
//
#include <hip/hip_runtime.h>

// ---------------------------------------------------------------------------
// MRLR feature extractor, round 9.
//   W1 = proj(M^14 C1): S1=M^2*2^-27, S2=S1^2, S3=S2^2, Q = S3*(S2*(S1*C1))
//   TMP = M - W1 M; M2 = TMP - TMP W1; W2 = proj(M2^14 (C2 - W1 C2))
//   T = W1 + W2;  out = T X.
// k1: split-K partials, nch=128 WGs/item, LDS red aliased w/ staging (38.4KB
//     -> 4 WG/CU).  k2: reduce (150x128).  kw_phase x8: wide GEMM phases.
// kWproj x2: per-row-slab wide kernel doing Q=S3P + Gram + wave-GJ + W=QKQ^T
//     (redundant small work per WG; no 8-WG latency kernel remains).
// k4: out = T X.
// ---------------------------------------------------------------------------

#define TID ((int)threadIdx.x)
typedef float4 f4;

#define SC27 (1.0f/134217728.0f)   // 2^-27

__device__ __forceinline__ f4 ld4(const float* p) { return *(const f4*)p; }
__device__ __forceinline__ void st4(float* p, f4 v) { *(f4*)p = v; }
__device__ __forceinline__ f4 f4zero() { return make_float4(0.f,0.f,0.f,0.f); }
__device__ __forceinline__ f4 add4(f4 a, f4 b){ return make_float4(a.x+b.x,a.y+b.y,a.z+b.z,a.w+b.w); }
__device__ __forceinline__ f4 sub4(f4 a, f4 b){ return make_float4(a.x-b.x,a.y-b.y,a.z-b.z,a.w-b.w); }
__device__ __forceinline__ f4 scl4(f4 a, float s){ return make_float4(a.x*s,a.y*s,a.z*s,a.w*s); }
__device__ __forceinline__ void fma4(f4& a, float s, f4 v) {
  a.x = fmaf(s,v.x,a.x); a.y = fmaf(s,v.y,a.y); a.z = fmaf(s,v.z,a.z); a.w = fmaf(s,v.w,a.w);
}
__device__ __forceinline__ float dot4(f4 a, f4 b, float acc) {
  acc = fmaf(a.x,b.x,acc); acc = fmaf(a.y,b.y,acc);
  acc = fmaf(a.z,b.z,acc); acc = fmaf(a.w,b.w,acc); return acc;
}
__device__ __forceinline__ void trimap(int t, int& ti, int& tj) {
  int rem = t; ti = 0;
  #pragma unroll
  for (int r = 0; r < 12; ++r) { int w = 12 - r; if (rem < w) { ti = r; break; } rem -= w; }
  tj = ti + rem;
}
__device__ __forceinline__ void init8(f4 acc[8][2]) {
  #pragma unroll
  for (int a = 0; a < 8; ++a) { acc[a][0] = f4zero(); acc[a][1] = f4zero(); }
}
__device__ __forceinline__ void tile8_step(f4 acc[8][2], const float* u, const float* v) {
  f4 u0 = ld4(u), u1 = ld4(u+4), v0 = ld4(v), v1 = ld4(v+4);
  float aa[8] = {u0.x,u0.y,u0.z,u0.w,u1.x,u1.y,u1.z,u1.w};
  #pragma unroll
  for (int a = 0; a < 8; ++a) { fma4(acc[a][0], aa[a], v0); fma4(acc[a][1], aa[a], v1); }
}

// ---------------------------------------------------------------------------
// k1: grid (nch, 8), block 512.  450 active: 3 k-parity x (78 tri-M + 72 C).
// Sub-chunks of 24 k.  LDS: staging (Xst 9.6KB + Bs 5KB) aliased with the
// 38.4KB reduce buffer (reduce runs only after all compute) -> 4 WG/CU.
// ---------------------------------------------------------------------------
__global__ __launch_bounds__(512) void k1_partials(
    const float* __restrict__ x, const float* __restrict__ b01,
    const float* __restrict__ b02, float* __restrict__ part,
    int nch, int nsc) {
  __shared__ __align__(16) float smem[9600];          // 38.4 KB
  float (*Xst)[100] = (float (*)[100])smem;           // [24][100]
  float (*Bs)[52]   = (float (*)[52])(smem + 2400);   // [24][52]
  float* red = smem;                                  // aliased (used at end)

  int kc = blockIdx.x, item = blockIdx.y;
  const float* X = x + (size_t)item * 96 * 9216;
  float* base = part + (size_t)(item * nch + kc) * 9600;

  int t = TID, kh = 0, tt = 0;
  const float* ap = nullptr; const float* bp = nullptr;
  float* op = nullptr; int os = 0; bool isM = false;
  bool active = (t < 450);
  if (active) {
    kh = t / 150; tt = t % 150;
    if (tt < 78) {
      int ti, tj; trimap(tt, ti, tj);
      ap = &Xst[0][ti*8]; bp = &Xst[0][tj*8];
      op = base + tt*64; os = 8; isM = true;
    } else {
      int u = tt - 78; int i0 = (u/6)*8, c0 = (u%6)*8;
      ap = &Xst[0][i0]; bp = &Bs[0][c0];
      op = base + 4992 + i0*48 + c0; os = 48;
    }
  }

  f4 acc[8][2]; init8(acc);

  for (int sc = 0; sc < nsc; ++sc) {
    int k0 = (kc * nsc + sc) * 24;
    __syncthreads();
    for (int e = TID; e < 576; e += 512) {           // X slab transposed (24k)
      int i = e / 6, kq = (e % 6) * 4;
      f4 v = ld4(&X[(size_t)i * 9216 + k0 + kq]);
      Xst[kq][i] = v.x; Xst[kq+1][i] = v.y; Xst[kq+2][i] = v.z; Xst[kq+3][i] = v.w;
    }
    if (TID < 192) {                                 // B01 (24x32)
      int kk = TID / 8, cq = (TID % 8) * 4;
      st4(&Bs[kk][cq], ld4(&b01[(size_t)(k0 + kk) * 32 + cq]));
    } else if (TID < 288) {                          // B02 (24x16)
      int e = TID - 192; int kk = e / 4, cq = (e % 4) * 4;
      st4(&Bs[kk][32+cq], ld4(&b02[(size_t)(k0 + kk) * 16 + cq]));
    }
    __syncthreads();
    if (active) {
      int asr = 100, bsr = isM ? 100 : 52;
      const float* ar = ap + kh * asr;
      const float* br = bp + kh * bsr;
      #pragma unroll 4
      for (int kk = kh; kk < 24; kk += 3) {
        tile8_step(acc, ar, br);
        ar += 3 * asr; br += 3 * bsr;
      }
    }
  }
  // 2-hop reduce into red (aliases staging; all compute is done)
  __syncthreads();
  if (active && kh == 1) {
    #pragma unroll
    for (int a = 0; a < 8; ++a) { st4(&red[tt*64+a*8], acc[a][0]); st4(&red[tt*64+a*8+4], acc[a][1]); }
  }
  __syncthreads();
  if (active && kh == 0) {
    #pragma unroll
    for (int a = 0; a < 8; ++a) {
      acc[a][0] = add4(acc[a][0], ld4(&red[tt*64+a*8]));
      acc[a][1] = add4(acc[a][1], ld4(&red[tt*64+a*8+4]));
    }
  }
  __syncthreads();
  if (active && kh == 2) {
    #pragma unroll
    for (int a = 0; a < 8; ++a) { st4(&red[tt*64+a*8], acc[a][0]); st4(&red[tt*64+a*8+4], acc[a][1]); }
  }
  __syncthreads();
  if (active && kh == 0) {
    #pragma unroll
    for (int a = 0; a < 8; ++a) {
      f4 s0 = add4(acc[a][0], ld4(&red[tt*64+a*8]));
      f4 s1 = add4(acc[a][1], ld4(&red[tt*64+a*8+4]));
      st4(op + a*os, s0); st4(op + a*os + 4, s1);
    }
  }
}

// ---------------------------------------------------------------------------
// k2: reduce nch partials -> M unpacked (mirrored) + C.  grid 150 x 128.
// ---------------------------------------------------------------------------
__global__ __launch_bounds__(128) void k2_reduce(
    const float* __restrict__ part, float* __restrict__ Mb,
    float* __restrict__ Cb, int nch) {
  int gid = blockIdx.x * 128 + TID;       // < 19200
  int item = gid / 2400, q4 = gid % 2400;
  int off = q4 * 4;
  const float* p = part + (size_t)item * nch * 9600 + off;
  f4 s = f4zero();
  #pragma unroll 16
  for (int c = 0; c < nch; ++c) s = add4(s, ld4(p + (size_t)c * 9600));
  if (off < 4992) {
    int tile = off >> 6, w = (off & 63) >> 2;
    int r = w >> 1, cq = (w & 1) * 4;
    int ti, tj; trimap(tile, ti, tj);
    int i = ti*8 + r, j = tj*8 + cq;
    float* Mi = Mb + (size_t)item * 9216;
    st4(&Mi[i*96 + j], s);
    Mi[(j+0)*96 + i] = s.x; Mi[(j+1)*96 + i] = s.y;
    Mi[(j+2)*96 + i] = s.z; Mi[(j+3)*96 + i] = s.w;
  } else {
    st4(&Cb[(size_t)item * 4608 + (off - 4992)], s);
  }
}

// ---------------------------------------------------------------------------
// kw_phase: wide GEMM phase.  grid (12 or 13, 8), block 256.  (verified r6-8)
// ---------------------------------------------------------------------------
__global__ __launch_bounds__(256) void kw_phase(
    const float* __restrict__ Ag, const float* __restrict__ Bg,
    const float* __restrict__ Subg, float* __restrict__ Dg, float scale,
    const float* __restrict__ Tin, int ti_istr, int tis, int tsub,
    float* __restrict__ Tout, int to_istr, int tos, int TW) {
  int w = blockIdx.x, item = blockIdx.y;
  const float* A = Ag + (size_t)item * 9216;
  if (w < 12) {
    if (TID >= 192) return;
    const float* B = Bg + (size_t)item * 9216;
    float* D = Dg + (size_t)item * 9216;
    int r = w*8 + TID/24, jb = (TID%24)*4;
    const float* arow = A + r*96;
    f4 acc = f4zero();
    #pragma unroll 8
    for (int k = 0; k < 96; ++k) fma4(acc, arow[k], ld4(&B[k*96 + jb]));
    if (Subg) acc = sub4(ld4(&Subg[(size_t)item*9216 + r*96 + jb]), acc);
    else      acc = scl4(acc, scale);
    st4(&D[r*96 + jb], acc);
  } else {
    int nact = (TW == 32) ? 192 : 96;
    if (TID >= nact) return;
    int r  = (TW == 32) ? (TID >> 1) : TID;
    int c0 = (TW == 32) ? (TID & 1) * 16 : 0;
    const float* Ti = Tin + (size_t)item * ti_istr;
    float* To = Tout + (size_t)item * to_istr;
    const float* arow = A + r*96;
    f4 acc[4] = {f4zero(), f4zero(), f4zero(), f4zero()};
    #pragma unroll 4
    for (int k = 0; k < 96; ++k) {
      float a = arow[k];
      const float* tr = Ti + (size_t)k * tis + c0;
      fma4(acc[0], a, ld4(tr));   fma4(acc[1], a, ld4(tr+4));
      fma4(acc[2], a, ld4(tr+8)); fma4(acc[3], a, ld4(tr+12));
    }
    if (tsub) {
      const float* sr = Ti + (size_t)r * tis + c0;
      #pragma unroll
      for (int u = 0; u < 4; ++u) acc[u] = sub4(ld4(sr + u*4), acc[u]);
    }
    #pragma unroll
    for (int u = 0; u < 4; ++u) st4(&To[(size_t)r * tos + c0 + u*4], acc[u]);
  }
}

// ---------------------------------------------------------------------------
// Wave-register Gauss-Jordan (verified r7/r8).
// ---------------------------------------------------------------------------
template<int R>
__device__ void gj_wave(float (*aug)[64], int lane) {
  float col[R];
  if (lane < R) {
    #pragma unroll
    for (int i = 0; i < R; ++i) col[i] = aug[i][lane];
  } else {
    #pragma unroll
    for (int i = 0; i < R; ++i) col[i] = (i == lane - R) ? 1.f : 0.f;
  }
  #pragma unroll
  for (int c = 0; c < R; ++c) {
    float pc = __shfl(col[c], c);
    float rp = 1.f / pc;
    bool isc = (lane == c);
    #pragma unroll
    for (int i = 0; i < R; ++i) {
      if (i == c) continue;
      float fi = __shfl(col[i], c) * rp;
      float v = fmaf(-fi, col[c], col[i]);
      col[i] = isc ? 0.f : v;
    }
  }
  #pragma unroll
  for (int i = 0; i < R; ++i) {
    float d = __shfl(col[i], i);
    col[i] = col[i] / d;
  }
  if (lane >= R) {
    #pragma unroll
    for (int i = 0; i < R; ++i) aug[i][lane] = col[i];
  }
}

// ---------------------------------------------------------------------------
// kWproj<TW,MODE>: wide projector build.  grid (12, 8), block 256.
// Each WG: P->LDS; Q = S3*P (full, redundant); Gram = Q^T Q; wave-GJ -> K;
// QK slab (8 rows); W slab = QK * Q^T.  MODE 1: W -> W1g.  MODE 2:
// Tg = W1g + W.
// ---------------------------------------------------------------------------
template<int TW, int MODE>
__global__ __launch_bounds__(256) void kWproj(
    const float* __restrict__ S3g, const float* __restrict__ Pg,
    float* __restrict__ W1g, float* __restrict__ Tgg) {
  __shared__ __align__(16) float Ps[96][TW];
  __shared__ __align__(16) float Qs[96][TW];
  __shared__ __align__(16) float aug[32][64];
  __shared__ __align__(16) float QKs[8][TW];

  int w = blockIdx.x, item = blockIdx.y, t = TID;
  const float* S3 = S3g + (size_t)item * 9216;
  const float* P  = Pg  + (size_t)item * 3072;   // rows stride 32
  float* W1 = W1g + (size_t)item * 9216;
  float* Tg = Tgg + (size_t)item * 9216;

  // s0: P -> LDS
  for (int e = t*4; e < 96*TW; e += 1024) {
    int r = e / TW, c = e % TW;
    st4(&Ps[r][c], ld4(&P[r*32 + c]));
  }
  __syncthreads();

  // s1: Q = S3 * P (full 96 x TW, redundant per WG)
  {
    const int ng = TW >> 2;
    for (int e = t; e < 96*ng; e += 256) {
      int r = e / ng, c4 = (e % ng) * 4;
      const float* srow = S3 + r*96;
      f4 acc = f4zero();
      #pragma unroll 4
      for (int k = 0; k < 96; ++k) fma4(acc, srow[k], ld4(&Ps[k][c4]));
      st4(&Qs[r][c4], acc);
    }
  }
  __syncthreads();

  // s2: Gram = Qs^T Qs -> aug[:,0:TW]
  {
    const int ng = TW >> 2;
    for (int e = t; e < TW*ng; e += 256) {
      int ar = e / ng, b4 = (e % ng) * 4;
      f4 acc = f4zero();
      #pragma unroll 4
      for (int k = 0; k < 96; ++k) fma4(acc, Qs[k][ar], ld4(&Qs[k][b4]));
      st4(&aug[ar][b4], acc);
    }
  }
  __syncthreads();

  // s3: wave-GJ (wave 0) -> K in aug[:,TW:2TW]
  if (t < 2*TW) gj_wave<TW>(aug, t);
  __syncthreads();
  // s3b: K^T -> aug[:,0:TW]
  for (int e = t; e < TW*TW; e += 256) { int m = e/TW, c = e%TW; aug[c][m] = aug[m][TW+c]; }
  __syncthreads();

  // s4: QK slab for rows [w*8, w*8+8)
  for (int e = t; e < 8*TW; e += 256) {
    int rr = e / TW, c = e % TW;
    const float* qrow = &Qs[w*8 + rr][0];
    float acc = 0.f;
    #pragma unroll
    for (int m4 = 0; m4 < TW; m4 += 4)
      acc = dot4(ld4(&qrow[m4]), ld4(&aug[c][m4]), acc);
    QKs[rr][c] = acc;
  }
  __syncthreads();

  // s5: W slab = QKs * Qs^T  (8 x 96)
  if (t < 192) {
    int rr = t / 24, jb = (t % 24) * 4;
    int r = w*8 + rr;
    f4 acc = f4zero();
    #pragma unroll
    for (int c4 = 0; c4 < TW; c4 += 4) {
      f4 qk = ld4(&QKs[rr][c4]);
      acc.x = dot4(qk, ld4(&Qs[jb+0][c4]), acc.x);
      acc.y = dot4(qk, ld4(&Qs[jb+1][c4]), acc.y);
      acc.z = dot4(qk, ld4(&Qs[jb+2][c4]), acc.z);
      acc.w = dot4(qk, ld4(&Qs[jb+3][c4]), acc.w);
    }
    if (MODE == 1) st4(&W1[r*96 + jb], acc);
    else           st4(&Tg[r*96 + jb], add4(acc, ld4(&W1[r*96 + jb])));
  }
}

// ---------------------------------------------------------------------------
// k4: out = T @ X.  grid (72, 8), block 256.
// ---------------------------------------------------------------------------
__global__ __launch_bounds__(256) void k4_out(
    const float* __restrict__ x, const float* __restrict__ Tgg,
    float* __restrict__ out) {
  __shared__ __align__(16) float Tt[96][100];
  int jb = blockIdx.x, item = blockIdx.y;
  const float* Tg = Tgg + (size_t)item * 9216;
  for (int e = TID * 4; e < 9216; e += 1024) {
    f4 v = ld4(&Tg[e]);
    int i = e / 96, k = e % 96;
    Tt[k][i] = v.x; Tt[k+1][i] = v.y; Tt[k+2][i] = v.z; Tt[k+3][i] = v.w;
  }
  __syncthreads();

  int jq = (TID % 32) * 4, ig = TID / 32;
  int i0 = ig * 12;
  int col = jb * 128 + jq;
  const float* X = x + (size_t)item * 96 * 9216;
  f4 acc[12];
  #pragma unroll
  for (int a = 0; a < 12; ++a) acc[a] = f4zero();

  for (int k = 0; k < 96; ++k) {
    f4 xv = ld4(&X[(size_t)k * 9216 + col]);
    f4 t0 = ld4(&Tt[k][i0]), t1 = ld4(&Tt[k][i0+4]), t2 = ld4(&Tt[k][i0+8]);
    fma4(acc[0], t0.x, xv); fma4(acc[1], t0.y, xv); fma4(acc[2], t0.z, xv); fma4(acc[3], t0.w, xv);
    fma4(acc[4], t1.x, xv); fma4(acc[5], t1.y, xv); fma4(acc[6], t1.z, xv); fma4(acc[7], t1.w, xv);
    fma4(acc[8], t2.x, xv); fma4(acc[9], t2.y, xv); fma4(acc[10], t2.z, xv); fma4(acc[11], t2.w, xv);
  }
  float* O = out + (size_t)item * 96 * 9216;
  #pragma unroll
  for (int a = 0; a < 12; ++a) st4(&O[(size_t)(i0 + a) * 9216 + col], acc[a]);
}

// ---------------------------------------------------------------------------
extern "C" void kernel_launch(void* const* d_in, const int* in_sizes, int n_in,
                              void* d_out, int out_size, void* d_ws, size_t ws_size,
                              hipStream_t stream) {
  (void)in_sizes; (void)n_in; (void)out_size;
  const float* x   = (const float*)d_in[0];
  const float* b01 = (const float*)d_in[2];
  const float* b02 = (const float*)d_in[4];
  float* out = (float*)d_out;
  float* ws  = (float*)d_ws;

  // M, C, S(=TMP), S2, S3, W1, Tg, P, Y, CP
  const size_t EXTRA = 73728ull*6 + 36864 + 24576*2 + 12288;   // 540,672 floats
  int nch = 32;
  if (ws_size >= ((size_t)128*8*9600 + EXTRA) * sizeof(float))      nch = 128;
  else if (ws_size >= ((size_t)64*8*9600 + EXTRA) * sizeof(float))  nch = 64;
  int nsc = 9216 / (nch * 24);

  float* Mb  = ws + (size_t)nch * 8 * 9600;
  float* Cb  = Mb  + 73728;
  float* Sb  = Cb  + 36864;    // S1 / S1' ; aliased as TMP
  float* S2b = Sb  + 73728;
  float* S3b = S2b + 73728;
  float* W1b = S3b + 73728;
  float* Tgb = W1b + 73728;
  float* Pb  = Tgb + 73728;
  float* Yb  = Pb  + 24576;
  float* CPb = Yb  + 24576;

  k1_partials<<<dim3(nch, 8), 512, 0, stream>>>(x, b01, b02, ws, nch, nsc);
  k2_reduce<<<dim3(150), 128, 0, stream>>>(ws, Mb, Cb, nch);

  // partition 1
  kw_phase<<<dim3(12,8),256,0,stream>>>(Mb, Mb, nullptr, Sb, SC27,
      nullptr,0,0,0, nullptr,0,0, 0);                                   // S1 = M^2*s
  kw_phase<<<dim3(13,8),256,0,stream>>>(Sb, Sb, nullptr, S2b, 1.f,
      Cb,4608,48,0, Yb,3072,32, 32);                                    // S2 ; Y = S1*C1
  kw_phase<<<dim3(13,8),256,0,stream>>>(S2b, S2b, nullptr, S3b, 1.f,
      Yb,3072,32,0, Pb,3072,32, 32);                                    // S3 ; P = S2*Y
  kWproj<32,1><<<dim3(12,8),256,0,stream>>>(S3b, Pb, W1b, Tgb);         // W1

  // M2 construction
  kw_phase<<<dim3(13,8),256,0,stream>>>(W1b, Mb, Mb, Sb, 1.f,
      Cb+32,4608,48,1, CPb,1536,16, 16);                                // TMP = M - W1*M ; C2'
  kw_phase<<<dim3(12,8),256,0,stream>>>(Sb, W1b, Sb, Mb, 1.f,
      nullptr,0,0,0, nullptr,0,0, 0);                                   // M2 = TMP - TMP*W1

  // partition 2
  kw_phase<<<dim3(12,8),256,0,stream>>>(Mb, Mb, nullptr, Sb, SC27,
      nullptr,0,0,0, nullptr,0,0, 0);                                   // S1' = M2^2*s
  kw_phase<<<dim3(13,8),256,0,stream>>>(Sb, Sb, nullptr, S2b, 1.f,
      CPb,1536,16,0, Yb,3072,32, 16);                                   // S2' ; Y = S1'*C2'
  kw_phase<<<dim3(13,8),256,0,stream>>>(S2b, S2b, nullptr, S3b, 1.f,
      Yb,3072,32,0, Pb,3072,32, 16);                                    // S3' ; P = S2'*Y
  kWproj<16,2><<<dim3(12,8),256,0,stream>>>(S3b, Pb, W1b, Tgb);         // Tg = W1+W2

  k4_out<<<dim3(72, 8), 256, 0, stream>>>(x, Tgb, out);
}

// Round 10
// 233.820 us; speedup vs baseline: 1.0525x; 1.0129x over previous
//
#include <hip/hip_runtime.h>

// ---------------------------------------------------------------------------
// MRLR feature extractor, round 10.
//   W1 = proj(M^14 C1): S1=M^2*2^-27, S2=S1^2, S3=S2^2, Q = S3*(S2*(S1*C1))
//   TMP = M - W1 M; M2 = TMP - TMP W1; W2 = proj(M2^14 (C2 - W1 C2))
//   T = W1 + W2;  out = T X.
// k1: global-direct (no staging): M-tiles = row-row dot4 from L1; C-tiles
//     row x B01/B02 rows.  2 k-parity halves, LDS reduce at end.  VALU-bound.
// k2: reduce partials.  kw_phase x8 / kWproj x2: operands STAGED IN LDS
//     (parallel fill) so no per-thread global latency chains.  k4: T X.
// ---------------------------------------------------------------------------

#define TID ((int)threadIdx.x)
typedef float4 f4;

#define SC27 (1.0f/134217728.0f)   // 2^-27

__device__ __forceinline__ f4 ld4(const float* p) { return *(const f4*)p; }
__device__ __forceinline__ void st4(float* p, f4 v) { *(f4*)p = v; }
__device__ __forceinline__ f4 f4zero() { return make_float4(0.f,0.f,0.f,0.f); }
__device__ __forceinline__ f4 add4(f4 a, f4 b){ return make_float4(a.x+b.x,a.y+b.y,a.z+b.z,a.w+b.w); }
__device__ __forceinline__ f4 sub4(f4 a, f4 b){ return make_float4(a.x-b.x,a.y-b.y,a.z-b.z,a.w-b.w); }
__device__ __forceinline__ f4 scl4(f4 a, float s){ return make_float4(a.x*s,a.y*s,a.z*s,a.w*s); }
__device__ __forceinline__ void fma4(f4& a, float s, f4 v) {
  a.x = fmaf(s,v.x,a.x); a.y = fmaf(s,v.y,a.y); a.z = fmaf(s,v.z,a.z); a.w = fmaf(s,v.w,a.w);
}
__device__ __forceinline__ float getc(f4 v, int u) {
  return u==0 ? v.x : (u==1 ? v.y : (u==2 ? v.z : v.w));
}
__device__ __forceinline__ float dot4(f4 a, f4 b, float acc) {
  acc = fmaf(a.x,b.x,acc); acc = fmaf(a.y,b.y,acc);
  acc = fmaf(a.z,b.z,acc); acc = fmaf(a.w,b.w,acc); return acc;
}
__device__ __forceinline__ void trimap(int t, int& ti, int& tj) {
  int rem = t; ti = 0;
  #pragma unroll
  for (int r = 0; r < 12; ++r) { int w = 12 - r; if (rem < w) { ti = r; break; } rem -= w; }
  tj = ti + rem;
}

// ---------------------------------------------------------------------------
// k1: grid (nch, 8), block 320.  300 active: 2 k-parity x (78 tri-M + 72 C).
// No input staging: M-tiles read X rows direct (L1 broadcast across lanes),
// C-tiles read X rows + B01/B02 rows (L2-hot).  LDS only for k-parity reduce.
// ---------------------------------------------------------------------------
__global__ __launch_bounds__(320) void k1_partials(
    const float* __restrict__ x, const float* __restrict__ b01,
    const float* __restrict__ b02, float* __restrict__ part, int nch) {
  __shared__ __align__(16) float red[9600];
  int kc = blockIdx.x, item = blockIdx.y;
  const float* X = x + (size_t)item * 96 * 9216;
  float* base = part + (size_t)(item * nch + kc) * 9600;

  int t = TID;
  bool active = (t < 300);
  int kh = (t >= 150) ? 1 : 0, tt = t % 150;
  int KB = 9216 / nch;                 // k per WG (144 at nch=64)
  int iters = KB >> 3;                 // quads of 4, stride 8 (2 parities)
  int k0 = kc * KB + kh * 4;

  f4 out[8][2];
  #pragma unroll
  for (int i = 0; i < 8; ++i) { out[i][0] = f4zero(); out[i][1] = f4zero(); }

  float* op = nullptr; int os = 0;

  if (active && tt < 78) {             // ---- M tri-tile (8x8) ----
    int ti, tj; trimap(tt, ti, tj);
    const float* Xa = X + (size_t)(ti * 8) * 9216;
    const float* Xb = X + (size_t)(tj * 8) * 9216;
    op = base + tt * 64; os = 8;
    float acc[8][8];
    #pragma unroll
    for (int i = 0; i < 8; ++i)
      #pragma unroll
      for (int j = 0; j < 8; ++j) acc[i][j] = 0.f;
    for (int q = 0; q < iters; ++q) {
      int k = k0 + q * 8;
      f4 a[8], b[8];
      #pragma unroll
      for (int i = 0; i < 8; ++i) a[i] = ld4(&Xa[(size_t)i * 9216 + k]);
      #pragma unroll
      for (int j = 0; j < 8; ++j) b[j] = ld4(&Xb[(size_t)j * 9216 + k]);
      #pragma unroll
      for (int i = 0; i < 8; ++i)
        #pragma unroll
        for (int j = 0; j < 8; ++j) acc[i][j] = dot4(a[i], b[j], acc[i][j]);
    }
    #pragma unroll
    for (int i = 0; i < 8; ++i) {
      out[i][0] = make_float4(acc[i][0], acc[i][1], acc[i][2], acc[i][3]);
      out[i][1] = make_float4(acc[i][4], acc[i][5], acc[i][6], acc[i][7]);
    }
  } else if (active) {                 // ---- C tile (8x8 of 96x48) ----
    int u = tt - 78; int i0 = (u / 6) * 8, c0 = (u % 6) * 8;
    const float* Xa = X + (size_t)i0 * 9216;
    const float* Bsrc = (c0 < 32) ? (b01 + c0) : (b02 + (c0 - 32));
    int bs = (c0 < 32) ? 32 : 16;
    op = base + 4992 + i0 * 48 + c0; os = 48;
    for (int q = 0; q < iters; ++q) {
      int k = k0 + q * 8;
      f4 a[8];
      #pragma unroll
      for (int i = 0; i < 8; ++i) a[i] = ld4(&Xa[(size_t)i * 9216 + k]);
      #pragma unroll
      for (int kk = 0; kk < 4; ++kk) {
        f4 br0 = ld4(&Bsrc[(size_t)(k + kk) * bs]);
        f4 br1 = ld4(&Bsrc[(size_t)(k + kk) * bs + 4]);
        #pragma unroll
        for (int i = 0; i < 8; ++i) {
          float av = getc(a[i], kk);
          fma4(out[i][0], av, br0); fma4(out[i][1], av, br1);
        }
      }
    }
  }

  __syncthreads();
  if (active && kh == 1) {
    #pragma unroll
    for (int i = 0; i < 8; ++i) {
      st4(&red[tt*64 + i*8], out[i][0]); st4(&red[tt*64 + i*8 + 4], out[i][1]);
    }
  }
  __syncthreads();
  if (active && kh == 0) {
    #pragma unroll
    for (int i = 0; i < 8; ++i) {
      f4 s0 = add4(out[i][0], ld4(&red[tt*64 + i*8]));
      f4 s1 = add4(out[i][1], ld4(&red[tt*64 + i*8 + 4]));
      st4(op + i*os, s0); st4(op + i*os + 4, s1);
    }
  }
}

// ---------------------------------------------------------------------------
// k2: reduce nch partials -> M unpacked (mirrored) + C.  grid 150 x 128.
// ---------------------------------------------------------------------------
__global__ __launch_bounds__(128) void k2_reduce(
    const float* __restrict__ part, float* __restrict__ Mb,
    float* __restrict__ Cb, int nch) {
  int gid = blockIdx.x * 128 + TID;       // < 19200
  int item = gid / 2400, q4 = gid % 2400;
  int off = q4 * 4;
  const float* p = part + (size_t)item * nch * 9600 + off;
  f4 s = f4zero();
  #pragma unroll 8
  for (int c = 0; c < nch; ++c) s = add4(s, ld4(p + (size_t)c * 9600));
  if (off < 4992) {
    int tile = off >> 6, w = (off & 63) >> 2;
    int r = w >> 1, cq = (w & 1) * 4;
    int ti, tj; trimap(tile, ti, tj);
    int i = ti*8 + r, j = tj*8 + cq;
    float* Mi = Mb + (size_t)item * 9216;
    st4(&Mi[i*96 + j], s);
    Mi[(j+0)*96 + i] = s.x; Mi[(j+1)*96 + i] = s.y;
    Mi[(j+2)*96 + i] = s.z; Mi[(j+3)*96 + i] = s.w;
  } else {
    st4(&Cb[(size_t)item * 4608 + (off - 4992)], s);
  }
}

// ---------------------------------------------------------------------------
// kw_phase v2: wide GEMM phase with LDS-staged operands.  grid (12|13, 8),
// block 256.
// w<12 (square): stage B-full + A-slab; D = Sub - A B  or  scale*(A B).
// w==12 (thin):  stage A-full + Tin; Tout = [Tin -] A*Tin.
// ---------------------------------------------------------------------------
__global__ __launch_bounds__(256) void kw_phase(
    const float* __restrict__ Ag, const float* __restrict__ Bg,
    const float* __restrict__ Subg, float* __restrict__ Dg, float scale,
    const float* __restrict__ Tin, int ti_istr, int tis, int tsub,
    float* __restrict__ Tout, int to_istr, int tos, int TW) {
  __shared__ __align__(16) float Bs[96][100];   // B-full | A-full
  __shared__ __align__(16) float As[8][100];    // A-slab (square)
  __shared__ __align__(16) float Ts[96][36];    // Tin (thin)
  int w = blockIdx.x, item = blockIdx.y, t = TID;
  const float* A = Ag + (size_t)item * 9216;

  if (w < 12) {
    const float* B = Bg + (size_t)item * 9216;
    for (int e = t; e < 2304; e += 256) {            // stage B-full
      int r = e / 24, cq = (e % 24) * 4;
      st4(&Bs[r][cq], ld4(&B[r*96 + cq]));
    }
    if (t < 192) {                                   // stage A-slab
      int r = t / 24, cq = (t % 24) * 4;
      st4(&As[r][cq], ld4(&A[(size_t)(w*8 + r)*96 + cq]));
    }
    __syncthreads();
    if (t < 192) {
      int rl = t / 24, jb = (t % 24) * 4;
      f4 acc = f4zero();
      #pragma unroll 8
      for (int k = 0; k < 96; ++k) fma4(acc, As[rl][k], ld4(&Bs[k][jb]));
      int r = w*8 + rl;
      if (Subg) acc = sub4(ld4(&Subg[(size_t)item*9216 + r*96 + jb]), acc);
      else      acc = scl4(acc, scale);
      st4(&Dg[(size_t)item*9216 + r*96 + jb], acc);
    }
  } else {
    for (int e = t; e < 2304; e += 256) {            // stage A-full
      int r = e / 24, cq = (e % 24) * 4;
      st4(&Bs[r][cq], ld4(&A[r*96 + cq]));
    }
    int nq = TW >> 2;
    const float* Ti = Tin + (size_t)item * ti_istr;
    for (int e = t; e < 96*nq; e += 256) {           // stage Tin
      int r = e / nq, cq = (e % nq) * 4;
      st4(&Ts[r][cq], ld4(&Ti[(size_t)r * tis + cq]));
    }
    __syncthreads();
    int nact = (TW == 32) ? 192 : 96;
    if (t < nact) {
      int r  = (TW == 32) ? (t >> 1) : t;
      int c0 = (TW == 32) ? (t & 1) * 16 : 0;
      f4 acc[4] = {f4zero(), f4zero(), f4zero(), f4zero()};
      #pragma unroll 4
      for (int k = 0; k < 96; ++k) {
        float a = Bs[r][k];
        const float* tr = &Ts[k][c0];
        fma4(acc[0], a, ld4(tr));   fma4(acc[1], a, ld4(tr+4));
        fma4(acc[2], a, ld4(tr+8)); fma4(acc[3], a, ld4(tr+12));
      }
      if (tsub) {
        #pragma unroll
        for (int u = 0; u < 4; ++u) acc[u] = sub4(ld4(&Ts[r][c0 + u*4]), acc[u]);
      }
      float* To = Tout + (size_t)item * to_istr;
      #pragma unroll
      for (int u = 0; u < 4; ++u) st4(&To[(size_t)r * tos + c0 + u*4], acc[u]);
    }
  }
}

// ---------------------------------------------------------------------------
// Wave-register Gauss-Jordan (verified r7-r9).
// ---------------------------------------------------------------------------
template<int R>
__device__ void gj_wave(float (*aug)[64], int lane) {
  float col[R];
  if (lane < R) {
    #pragma unroll
    for (int i = 0; i < R; ++i) col[i] = aug[i][lane];
  } else {
    #pragma unroll
    for (int i = 0; i < R; ++i) col[i] = (i == lane - R) ? 1.f : 0.f;
  }
  #pragma unroll
  for (int c = 0; c < R; ++c) {
    float pc = __shfl(col[c], c);
    float rp = 1.f / pc;
    bool isc = (lane == c);
    #pragma unroll
    for (int i = 0; i < R; ++i) {
      if (i == c) continue;
      float fi = __shfl(col[i], c) * rp;
      float v = fmaf(-fi, col[c], col[i]);
      col[i] = isc ? 0.f : v;
    }
  }
  #pragma unroll
  for (int i = 0; i < R; ++i) {
    float d = __shfl(col[i], i);
    col[i] = col[i] / d;
  }
  if (lane >= R) {
    #pragma unroll
    for (int i = 0; i < R; ++i) aug[i][lane] = col[i];
  }
}

// ---------------------------------------------------------------------------
// kWproj<TW,MODE> v2: staged S3+P; Q=S3P + Gram + wave-GJ + W=QKQ^T.
// grid (12, 8), block 256.  MODE 1: W -> W1g.  MODE 2: Tg = W1g + W.
// ---------------------------------------------------------------------------
template<int TW, int MODE>
__global__ __launch_bounds__(256) void kWproj(
    const float* __restrict__ S3g, const float* __restrict__ Pg,
    float* __restrict__ W1g, float* __restrict__ Tgg) {
  __shared__ __align__(16) float S3s[96][100];
  __shared__ __align__(16) float Ps[96][32];
  __shared__ __align__(16) float Qs[96][32];
  __shared__ __align__(16) float aug[32][64];
  __shared__ __align__(16) float QKs[8][32];

  int w = blockIdx.x, item = blockIdx.y, t = TID;
  const float* S3 = S3g + (size_t)item * 9216;
  const float* P  = Pg  + (size_t)item * 3072;
  float* W1 = W1g + (size_t)item * 9216;
  float* Tg = Tgg + (size_t)item * 9216;
  const int nq = TW >> 2;

  // s0: stage S3 + P
  for (int e = t; e < 2304; e += 256) {
    int r = e / 24, cq = (e % 24) * 4;
    st4(&S3s[r][cq], ld4(&S3[r*96 + cq]));
  }
  for (int e = t; e < 96*nq; e += 256) {
    int r = e / nq, cq = (e % nq) * 4;
    st4(&Ps[r][cq], ld4(&P[r*32 + cq]));
  }
  __syncthreads();

  // s1: Q = S3 * P
  for (int e = t; e < 96*nq; e += 256) {
    int r = e / nq, c4 = (e % nq) * 4;
    f4 acc = f4zero();
    #pragma unroll 4
    for (int k = 0; k < 96; ++k) fma4(acc, S3s[r][k], ld4(&Ps[k][c4]));
    st4(&Qs[r][c4], acc);
  }
  __syncthreads();

  // s2: Gram = Qs^T Qs -> aug[:,0:TW]
  for (int e = t; e < TW*nq; e += 256) {
    int ar = e / nq, b4 = (e % nq) * 4;
    f4 acc = f4zero();
    #pragma unroll 4
    for (int k = 0; k < 96; ++k) fma4(acc, Qs[k][ar], ld4(&Qs[k][b4]));
    st4(&aug[ar][b4], acc);
  }
  __syncthreads();

  // s3: wave-GJ -> K in aug[:,TW:2TW]; transpose K^T -> aug[:,0:TW]
  if (t < 2*TW) gj_wave<TW>(aug, t);
  __syncthreads();
  for (int e = t; e < TW*TW; e += 256) { int m = e/TW, c = e%TW; aug[c][m] = aug[m][TW+c]; }
  __syncthreads();

  // s4: QK slab (rows w*8..w*8+8)
  for (int e = t; e < 8*TW; e += 256) {
    int rr = e / TW, c = e % TW;
    const float* qrow = &Qs[w*8 + rr][0];
    float acc = 0.f;
    #pragma unroll
    for (int m4 = 0; m4 < TW; m4 += 4)
      acc = dot4(ld4(&qrow[m4]), ld4(&aug[c][m4]), acc);
    QKs[rr][c] = acc;
  }
  __syncthreads();

  // s5: W slab = QKs * Qs^T
  if (t < 192) {
    int rr = t / 24, jb = (t % 24) * 4;
    int r = w*8 + rr;
    f4 acc = f4zero();
    #pragma unroll
    for (int c4 = 0; c4 < TW; c4 += 4) {
      f4 qk = ld4(&QKs[rr][c4]);
      acc.x = dot4(qk, ld4(&Qs[jb+0][c4]), acc.x);
      acc.y = dot4(qk, ld4(&Qs[jb+1][c4]), acc.y);
      acc.z = dot4(qk, ld4(&Qs[jb+2][c4]), acc.z);
      acc.w = dot4(qk, ld4(&Qs[jb+3][c4]), acc.w);
    }
    if (MODE == 1) st4(&W1[r*96 + jb], acc);
    else           st4(&Tg[r*96 + jb], add4(acc, ld4(&W1[r*96 + jb])));
  }
}

// ---------------------------------------------------------------------------
// k4: out = T @ X.  grid (72, 8), block 256.
// ---------------------------------------------------------------------------
__global__ __launch_bounds__(256) void k4_out(
    const float* __restrict__ x, const float* __restrict__ Tgg,
    float* __restrict__ out) {
  __shared__ __align__(16) float Tt[96][100];
  int jb = blockIdx.x, item = blockIdx.y;
  const float* Tg = Tgg + (size_t)item * 9216;
  for (int e = TID * 4; e < 9216; e += 1024) {
    f4 v = ld4(&Tg[e]);
    int i = e / 96, k = e % 96;
    Tt[k][i] = v.x; Tt[k+1][i] = v.y; Tt[k+2][i] = v.z; Tt[k+3][i] = v.w;
  }
  __syncthreads();

  int jq = (TID % 32) * 4, ig = TID / 32;
  int i0 = ig * 12;
  int col = jb * 128 + jq;
  const float* X = x + (size_t)item * 96 * 9216;
  f4 acc[12];
  #pragma unroll
  for (int a = 0; a < 12; ++a) acc[a] = f4zero();

  for (int k = 0; k < 96; ++k) {
    f4 xv = ld4(&X[(size_t)k * 9216 + col]);
    f4 t0 = ld4(&Tt[k][i0]), t1 = ld4(&Tt[k][i0+4]), t2 = ld4(&Tt[k][i0+8]);
    fma4(acc[0], t0.x, xv); fma4(acc[1], t0.y, xv); fma4(acc[2], t0.z, xv); fma4(acc[3], t0.w, xv);
    fma4(acc[4], t1.x, xv); fma4(acc[5], t1.y, xv); fma4(acc[6], t1.z, xv); fma4(acc[7], t1.w, xv);
    fma4(acc[8], t2.x, xv); fma4(acc[9], t2.y, xv); fma4(acc[10], t2.z, xv); fma4(acc[11], t2.w, xv);
  }
  float* O = out + (size_t)item * 96 * 9216;
  #pragma unroll
  for (int a = 0; a < 12; ++a) st4(&O[(size_t)(i0 + a) * 9216 + col], acc[a]);
}

// ---------------------------------------------------------------------------
extern "C" void kernel_launch(void* const* d_in, const int* in_sizes, int n_in,
                              void* d_out, int out_size, void* d_ws, size_t ws_size,
                              hipStream_t stream) {
  (void)in_sizes; (void)n_in; (void)out_size;
  const float* x   = (const float*)d_in[0];
  const float* b01 = (const float*)d_in[2];
  const float* b02 = (const float*)d_in[4];
  float* out = (float*)d_out;
  float* ws  = (float*)d_ws;

  const size_t EXTRA = 73728ull*6 + 36864 + 24576*2 + 12288;
  int nch = (ws_size >= ((size_t)64*8*9600 + EXTRA) * sizeof(float)) ? 64 : 32;

  float* Mb  = ws + (size_t)nch * 8 * 9600;
  float* Cb  = Mb  + 73728;
  float* Sb  = Cb  + 36864;    // S1 / S1' ; aliased as TMP
  float* S2b = Sb  + 73728;
  float* S3b = S2b + 73728;
  float* W1b = S3b + 73728;
  float* Tgb = W1b + 73728;
  float* Pb  = Tgb + 73728;
  float* Yb  = Pb  + 24576;
  float* CPb = Yb  + 24576;

  k1_partials<<<dim3(nch, 8), 320, 0, stream>>>(x, b01, b02, ws, nch);
  k2_reduce<<<dim3(150), 128, 0, stream>>>(ws, Mb, Cb, nch);

  // partition 1
  kw_phase<<<dim3(12,8),256,0,stream>>>(Mb, Mb, nullptr, Sb, SC27,
      nullptr,0,0,0, nullptr,0,0, 0);                                   // S1 = M^2*s
  kw_phase<<<dim3(13,8),256,0,stream>>>(Sb, Sb, nullptr, S2b, 1.f,
      Cb,4608,48,0, Yb,3072,32, 32);                                    // S2 ; Y = S1*C1
  kw_phase<<<dim3(13,8),256,0,stream>>>(S2b, S2b, nullptr, S3b, 1.f,
      Yb,3072,32,0, Pb,3072,32, 32);                                    // S3 ; P = S2*Y
  kWproj<32,1><<<dim3(12,8),256,0,stream>>>(S3b, Pb, W1b, Tgb);         // W1

  // M2 construction
  kw_phase<<<dim3(13,8),256,0,stream>>>(W1b, Mb, Mb, Sb, 1.f,
      Cb+32,4608,48,1, CPb,1536,16, 16);                                // TMP = M - W1*M ; C2'
  kw_phase<<<dim3(12,8),256,0,stream>>>(Sb, W1b, Sb, Mb, 1.f,
      nullptr,0,0,0, nullptr,0,0, 0);                                   // M2 = TMP - TMP*W1

  // partition 2
  kw_phase<<<dim3(12,8),256,0,stream>>>(Mb, Mb, nullptr, Sb, SC27,
      nullptr,0,0,0, nullptr,0,0, 0);                                   // S1' = M2^2*s
  kw_phase<<<dim3(13,8),256,0,stream>>>(Sb, Sb, nullptr, S2b, 1.f,
      CPb,1536,16,0, Yb,3072,32, 16);                                   // S2' ; Y = S1'*C2'
  kw_phase<<<dim3(13,8),256,0,stream>>>(S2b, S2b, nullptr, S3b, 1.f,
      Yb,3072,32,0, Pb,3072,32, 16);                                    // S3' ; P = S2'*Y
  kWproj<16,2><<<dim3(12,8),256,0,stream>>>(S3b, Pb, W1b, Tgb);         // Tg = W1+W2

  k4_out<<<dim3(72, 8), 256, 0, stream>>>(x, Tgb, out);
}

// Round 11
// 181.415 us; speedup vs baseline: 1.3565x; 1.2889x over previous
//
#include <hip/hip_runtime.h>

// ---------------------------------------------------------------------------
// MRLR feature extractor, round 11.
//   W1 = proj(M^14 C1): S1=M^2*2^-27, S2=S1^2, S3=S2^2, Q = S3*(S2*(S1*C1))
//   TMP = M - W1 M; M2 = TMP - TMP W1; W2 = proj(M2^14 (C2 - W1 C2))
//   T = W1 + W2;  out = T X.
// All grids 1-D with item = bid & 7  ->  item j pinned to XCD j (round-robin
// block->XCD): every intermediate stays in one XCD's L2 across the pipeline.
// k1: r8-proven LDS-staged split-K partials (3-way k-parity, 2-hop reduce).
// k2: reduce partials.  kw_phase x8 / kWproj x2: LDS-staged wide phases.
// k4: out = T X.
// ---------------------------------------------------------------------------

#define TID ((int)threadIdx.x)
typedef float4 f4;

#define SC27 (1.0f/134217728.0f)   // 2^-27

__device__ __forceinline__ f4 ld4(const float* p) { return *(const f4*)p; }
__device__ __forceinline__ void st4(float* p, f4 v) { *(f4*)p = v; }
__device__ __forceinline__ f4 f4zero() { return make_float4(0.f,0.f,0.f,0.f); }
__device__ __forceinline__ f4 add4(f4 a, f4 b){ return make_float4(a.x+b.x,a.y+b.y,a.z+b.z,a.w+b.w); }
__device__ __forceinline__ f4 sub4(f4 a, f4 b){ return make_float4(a.x-b.x,a.y-b.y,a.z-b.z,a.w-b.w); }
__device__ __forceinline__ f4 scl4(f4 a, float s){ return make_float4(a.x*s,a.y*s,a.z*s,a.w*s); }
__device__ __forceinline__ void fma4(f4& a, float s, f4 v) {
  a.x = fmaf(s,v.x,a.x); a.y = fmaf(s,v.y,a.y); a.z = fmaf(s,v.z,a.z); a.w = fmaf(s,v.w,a.w);
}
__device__ __forceinline__ float dot4(f4 a, f4 b, float acc) {
  acc = fmaf(a.x,b.x,acc); acc = fmaf(a.y,b.y,acc);
  acc = fmaf(a.z,b.z,acc); acc = fmaf(a.w,b.w,acc); return acc;
}
__device__ __forceinline__ void trimap(int t, int& ti, int& tj) {
  int rem = t; ti = 0;
  #pragma unroll
  for (int r = 0; r < 12; ++r) { int w = 12 - r; if (rem < w) { ti = r; break; } rem -= w; }
  tj = ti + rem;
}
__device__ __forceinline__ void init8(f4 acc[8][2]) {
  #pragma unroll
  for (int a = 0; a < 8; ++a) { acc[a][0] = f4zero(); acc[a][1] = f4zero(); }
}
__device__ __forceinline__ void tile8_step(f4 acc[8][2], const float* u, const float* v) {
  f4 u0 = ld4(u), u1 = ld4(u+4), v0 = ld4(v), v1 = ld4(v+4);
  float aa[8] = {u0.x,u0.y,u0.z,u0.w,u1.x,u1.y,u1.z,u1.w};
  #pragma unroll
  for (int a = 0; a < 8; ++a) { fma4(acc[a][0], aa[a], v0); fma4(acc[a][1], aa[a], v1); }
}

// ---------------------------------------------------------------------------
// k1 (r8-proven): grid nch*8 (1-D, item = bid&7), block 512.
// 450 active: 3 k-parity x (78 tri-M + 72 C).  2-hop LDS reduce.  67.6 KB.
// ---------------------------------------------------------------------------
__global__ __launch_bounds__(512) void k1_partials(
    const float* __restrict__ x, const float* __restrict__ b01,
    const float* __restrict__ b02, float* __restrict__ part,
    int nch, int nsc) {
  __shared__ __align__(16) float Xst[48][100];
  __shared__ __align__(16) float Bs[48][52];
  __shared__ __align__(16) float red[9600];
  int bid = blockIdx.x;
  int item = bid & 7, kc = bid >> 3;
  const float* X = x + (size_t)item * 96 * 9216;
  float* base = part + (size_t)(item * nch + kc) * 9600;

  int t = TID, kh = 0, tt = 0;
  const float* ap = nullptr; const float* bp = nullptr;
  float* op = nullptr; int os = 0; bool isM = false;
  bool active = (t < 450);
  if (active) {
    kh = t / 150; tt = t % 150;
    if (tt < 78) {
      int ti, tj; trimap(tt, ti, tj);
      ap = &Xst[0][ti*8]; bp = &Xst[0][tj*8];
      op = base + tt*64; os = 8; isM = true;
    } else {
      int u = tt - 78; int i0 = (u/6)*8, c0 = (u%6)*8;
      ap = &Xst[0][i0]; bp = &Bs[0][c0];
      op = base + 4992 + i0*48 + c0; os = 48;
    }
  }

  f4 acc[8][2]; init8(acc);

  for (int sc = 0; sc < nsc; ++sc) {
    int k0 = (kc * nsc + sc) * 48;
    __syncthreads();
    for (int e = TID; e < 1152; e += 512) {          // X slab transposed
      int i = e / 12, kq = (e % 12) * 4;
      f4 v = ld4(&X[(size_t)i * 9216 + k0 + kq]);
      Xst[kq][i] = v.x; Xst[kq+1][i] = v.y; Xst[kq+2][i] = v.z; Xst[kq+3][i] = v.w;
    }
    for (int e = TID; e < 384; e += 512) {           // B01
      int kk = e / 8, cq = (e % 8) * 4;
      st4(&Bs[kk][cq], ld4(&b01[(size_t)(k0 + kk) * 32 + cq]));
    }
    for (int e = TID; e < 192; e += 512) {           // B02
      int kk = e / 4, cq = (e % 4) * 4;
      st4(&Bs[kk][32+cq], ld4(&b02[(size_t)(k0 + kk) * 16 + cq]));
    }
    __syncthreads();
    if (active) {
      int asr = 100, bsr = isM ? 100 : 52;
      const float* ar = ap + kh * asr;
      const float* br = bp + kh * bsr;
      #pragma unroll 4
      for (int kk = kh; kk < 48; kk += 3) {
        tile8_step(acc, ar, br);
        ar += 3 * asr; br += 3 * bsr;
      }
    }
  }
  __syncthreads();
  if (active && kh == 1) {
    #pragma unroll
    for (int a = 0; a < 8; ++a) { st4(&red[tt*64+a*8], acc[a][0]); st4(&red[tt*64+a*8+4], acc[a][1]); }
  }
  __syncthreads();
  if (active && kh == 0) {
    #pragma unroll
    for (int a = 0; a < 8; ++a) {
      acc[a][0] = add4(acc[a][0], ld4(&red[tt*64+a*8]));
      acc[a][1] = add4(acc[a][1], ld4(&red[tt*64+a*8+4]));
    }
  }
  __syncthreads();
  if (active && kh == 2) {
    #pragma unroll
    for (int a = 0; a < 8; ++a) { st4(&red[tt*64+a*8], acc[a][0]); st4(&red[tt*64+a*8+4], acc[a][1]); }
  }
  __syncthreads();
  if (active && kh == 0) {
    #pragma unroll
    for (int a = 0; a < 8; ++a) {
      f4 s0 = add4(acc[a][0], ld4(&red[tt*64+a*8]));
      f4 s1 = add4(acc[a][1], ld4(&red[tt*64+a*8+4]));
      st4(op + a*os, s0); st4(op + a*os + 4, s1);
    }
  }
}

// ---------------------------------------------------------------------------
// k2: reduce nch partials -> M unpacked (mirrored) + C.
// grid 160 (1-D, item = bid&7), block 128 (120 active: 120 f4/chunk x 20).
// ---------------------------------------------------------------------------
__global__ __launch_bounds__(128) void k2_reduce(
    const float* __restrict__ part, float* __restrict__ Mb,
    float* __restrict__ Cb, int nch) {
  int bid = blockIdx.x;
  int item = bid & 7, chunk = bid >> 3;
  if (TID >= 120) return;
  int q4 = chunk * 120 + TID;             // < 2400
  int off = q4 * 4;
  const float* p = part + (size_t)item * nch * 9600 + off;
  f4 s = f4zero();
  #pragma unroll 8
  for (int c = 0; c < nch; ++c) s = add4(s, ld4(p + (size_t)c * 9600));
  if (off < 4992) {
    int tile = off >> 6, w = (off & 63) >> 2;
    int r = w >> 1, cq = (w & 1) * 4;
    int ti, tj; trimap(tile, ti, tj);
    int i = ti*8 + r, j = tj*8 + cq;
    float* Mi = Mb + (size_t)item * 9216;
    st4(&Mi[i*96 + j], s);
    Mi[(j+0)*96 + i] = s.x; Mi[(j+1)*96 + i] = s.y;
    Mi[(j+2)*96 + i] = s.z; Mi[(j+3)*96 + i] = s.w;
  } else {
    st4(&Cb[(size_t)item * 4608 + (off - 4992)], s);
  }
}

// ---------------------------------------------------------------------------
// kw_phase: LDS-staged wide GEMM phase.  grid nw*8 (1-D, item = bid&7),
// block 256.  w<12: square slab.  w==12: thin.
// ---------------------------------------------------------------------------
__global__ __launch_bounds__(256) void kw_phase(
    const float* __restrict__ Ag, const float* __restrict__ Bg,
    const float* __restrict__ Subg, float* __restrict__ Dg, float scale,
    const float* __restrict__ Tin, int ti_istr, int tis, int tsub,
    float* __restrict__ Tout, int to_istr, int tos, int TW) {
  __shared__ __align__(16) float Bs[96][100];   // B-full | A-full
  __shared__ __align__(16) float As[8][100];    // A-slab (square)
  __shared__ __align__(16) float Ts[96][36];    // Tin (thin)
  int bid = blockIdx.x;
  int item = bid & 7, w = bid >> 3, t = TID;
  const float* A = Ag + (size_t)item * 9216;

  if (w < 12) {
    const float* B = Bg + (size_t)item * 9216;
    for (int e = t; e < 2304; e += 256) {            // stage B-full
      int r = e / 24, cq = (e % 24) * 4;
      st4(&Bs[r][cq], ld4(&B[r*96 + cq]));
    }
    if (t < 192) {                                   // stage A-slab
      int r = t / 24, cq = (t % 24) * 4;
      st4(&As[r][cq], ld4(&A[(size_t)(w*8 + r)*96 + cq]));
    }
    __syncthreads();
    if (t < 192) {
      int rl = t / 24, jb = (t % 24) * 4;
      f4 acc = f4zero();
      #pragma unroll 8
      for (int k = 0; k < 96; ++k) fma4(acc, As[rl][k], ld4(&Bs[k][jb]));
      int r = w*8 + rl;
      if (Subg) acc = sub4(ld4(&Subg[(size_t)item*9216 + r*96 + jb]), acc);
      else      acc = scl4(acc, scale);
      st4(&Dg[(size_t)item*9216 + r*96 + jb], acc);
    }
  } else {
    for (int e = t; e < 2304; e += 256) {            // stage A-full
      int r = e / 24, cq = (e % 24) * 4;
      st4(&Bs[r][cq], ld4(&A[r*96 + cq]));
    }
    int nq = TW >> 2;
    const float* Ti = Tin + (size_t)item * ti_istr;
    for (int e = t; e < 96*nq; e += 256) {           // stage Tin
      int r = e / nq, cq = (e % nq) * 4;
      st4(&Ts[r][cq], ld4(&Ti[(size_t)r * tis + cq]));
    }
    __syncthreads();
    int nact = (TW == 32) ? 192 : 96;
    if (t < nact) {
      int r  = (TW == 32) ? (t >> 1) : t;
      int c0 = (TW == 32) ? (t & 1) * 16 : 0;
      f4 acc[4] = {f4zero(), f4zero(), f4zero(), f4zero()};
      #pragma unroll 4
      for (int k = 0; k < 96; ++k) {
        float a = Bs[r][k];
        const float* tr = &Ts[k][c0];
        fma4(acc[0], a, ld4(tr));   fma4(acc[1], a, ld4(tr+4));
        fma4(acc[2], a, ld4(tr+8)); fma4(acc[3], a, ld4(tr+12));
      }
      if (tsub) {
        #pragma unroll
        for (int u = 0; u < 4; ++u) acc[u] = sub4(ld4(&Ts[r][c0 + u*4]), acc[u]);
      }
      float* To = Tout + (size_t)item * to_istr;
      #pragma unroll
      for (int u = 0; u < 4; ++u) st4(&To[(size_t)r * tos + c0 + u*4], acc[u]);
    }
  }
}

// ---------------------------------------------------------------------------
// Wave-register Gauss-Jordan (verified r7-r10).
// ---------------------------------------------------------------------------
template<int R>
__device__ void gj_wave(float (*aug)[64], int lane) {
  float col[R];
  if (lane < R) {
    #pragma unroll
    for (int i = 0; i < R; ++i) col[i] = aug[i][lane];
  } else {
    #pragma unroll
    for (int i = 0; i < R; ++i) col[i] = (i == lane - R) ? 1.f : 0.f;
  }
  #pragma unroll
  for (int c = 0; c < R; ++c) {
    float pc = __shfl(col[c], c);
    float rp = 1.f / pc;
    bool isc = (lane == c);
    #pragma unroll
    for (int i = 0; i < R; ++i) {
      if (i == c) continue;
      float fi = __shfl(col[i], c) * rp;
      float v = fmaf(-fi, col[c], col[i]);
      col[i] = isc ? 0.f : v;
    }
  }
  #pragma unroll
  for (int i = 0; i < R; ++i) {
    float d = __shfl(col[i], i);
    col[i] = col[i] / d;
  }
  if (lane >= R) {
    #pragma unroll
    for (int i = 0; i < R; ++i) aug[i][lane] = col[i];
  }
}

// ---------------------------------------------------------------------------
// kWproj<TW,MODE>: staged S3+P; Q=S3P + Gram + wave-GJ + W=QKQ^T.
// grid 96 (1-D, item = bid&7), block 256.  MODE 1: W->W1g. 2: Tg = W1g + W.
// ---------------------------------------------------------------------------
template<int TW, int MODE>
__global__ __launch_bounds__(256) void kWproj(
    const float* __restrict__ S3g, const float* __restrict__ Pg,
    float* __restrict__ W1g, float* __restrict__ Tgg) {
  __shared__ __align__(16) float S3s[96][100];
  __shared__ __align__(16) float Ps[96][32];
  __shared__ __align__(16) float Qs[96][32];
  __shared__ __align__(16) float aug[32][64];
  __shared__ __align__(16) float QKs[8][32];

  int bid = blockIdx.x;
  int item = bid & 7, w = bid >> 3, t = TID;
  const float* S3 = S3g + (size_t)item * 9216;
  const float* P  = Pg  + (size_t)item * 3072;
  float* W1 = W1g + (size_t)item * 9216;
  float* Tg = Tgg + (size_t)item * 9216;
  const int nq = TW >> 2;

  // s0: stage S3 + P
  for (int e = t; e < 2304; e += 256) {
    int r = e / 24, cq = (e % 24) * 4;
    st4(&S3s[r][cq], ld4(&S3[r*96 + cq]));
  }
  for (int e = t; e < 96*nq; e += 256) {
    int r = e / nq, cq = (e % nq) * 4;
    st4(&Ps[r][cq], ld4(&P[r*32 + cq]));
  }
  __syncthreads();

  // s1: Q = S3 * P
  for (int e = t; e < 96*nq; e += 256) {
    int r = e / nq, c4 = (e % nq) * 4;
    f4 acc = f4zero();
    #pragma unroll 4
    for (int k = 0; k < 96; ++k) fma4(acc, S3s[r][k], ld4(&Ps[k][c4]));
    st4(&Qs[r][c4], acc);
  }
  __syncthreads();

  // s2: Gram = Qs^T Qs -> aug[:,0:TW]
  for (int e = t; e < TW*nq; e += 256) {
    int ar = e / nq, b4 = (e % nq) * 4;
    f4 acc = f4zero();
    #pragma unroll 4
    for (int k = 0; k < 96; ++k) fma4(acc, Qs[k][ar], ld4(&Qs[k][b4]));
    st4(&aug[ar][b4], acc);
  }
  __syncthreads();

  // s3: wave-GJ -> K in aug[:,TW:2TW]; K^T -> aug[:,0:TW]
  if (t < 2*TW) gj_wave<TW>(aug, t);
  __syncthreads();
  for (int e = t; e < TW*TW; e += 256) { int m = e/TW, c = e%TW; aug[c][m] = aug[m][TW+c]; }
  __syncthreads();

  // s4: QK slab (rows w*8..w*8+8)
  for (int e = t; e < 8*TW; e += 256) {
    int rr = e / TW, c = e % TW;
    const float* qrow = &Qs[w*8 + rr][0];
    float acc = 0.f;
    #pragma unroll
    for (int m4 = 0; m4 < TW; m4 += 4)
      acc = dot4(ld4(&qrow[m4]), ld4(&aug[c][m4]), acc);
    QKs[rr][c] = acc;
  }
  __syncthreads();

  // s5: W slab = QKs * Qs^T
  if (t < 192) {
    int rr = t / 24, jb = (t % 24) * 4;
    int r = w*8 + rr;
    f4 acc = f4zero();
    #pragma unroll
    for (int c4 = 0; c4 < TW; c4 += 4) {
      f4 qk = ld4(&QKs[rr][c4]);
      acc.x = dot4(qk, ld4(&Qs[jb+0][c4]), acc.x);
      acc.y = dot4(qk, ld4(&Qs[jb+1][c4]), acc.y);
      acc.z = dot4(qk, ld4(&Qs[jb+2][c4]), acc.z);
      acc.w = dot4(qk, ld4(&Qs[jb+3][c4]), acc.w);
    }
    if (MODE == 1) st4(&W1[r*96 + jb], acc);
    else           st4(&Tg[r*96 + jb], add4(acc, ld4(&W1[r*96 + jb])));
  }
}

// ---------------------------------------------------------------------------
// k4: out = T @ X.  grid 576 (1-D, item = bid&7), block 256.
// ---------------------------------------------------------------------------
__global__ __launch_bounds__(256) void k4_out(
    const float* __restrict__ x, const float* __restrict__ Tgg,
    float* __restrict__ out) {
  __shared__ __align__(16) float Tt[96][100];
  int bid = blockIdx.x;
  int item = bid & 7, jb = bid >> 3;
  const float* Tg = Tgg + (size_t)item * 9216;
  for (int e = TID * 4; e < 9216; e += 1024) {
    f4 v = ld4(&Tg[e]);
    int i = e / 96, k = e % 96;
    Tt[k][i] = v.x; Tt[k+1][i] = v.y; Tt[k+2][i] = v.z; Tt[k+3][i] = v.w;
  }
  __syncthreads();

  int jq = (TID % 32) * 4, ig = TID / 32;
  int i0 = ig * 12;
  int col = jb * 128 + jq;
  const float* X = x + (size_t)item * 96 * 9216;
  f4 acc[12];
  #pragma unroll
  for (int a = 0; a < 12; ++a) acc[a] = f4zero();

  for (int k = 0; k < 96; ++k) {
    f4 xv = ld4(&X[(size_t)k * 9216 + col]);
    f4 t0 = ld4(&Tt[k][i0]), t1 = ld4(&Tt[k][i0+4]), t2 = ld4(&Tt[k][i0+8]);
    fma4(acc[0], t0.x, xv); fma4(acc[1], t0.y, xv); fma4(acc[2], t0.z, xv); fma4(acc[3], t0.w, xv);
    fma4(acc[4], t1.x, xv); fma4(acc[5], t1.y, xv); fma4(acc[6], t1.z, xv); fma4(acc[7], t1.w, xv);
    fma4(acc[8], t2.x, xv); fma4(acc[9], t2.y, xv); fma4(acc[10], t2.z, xv); fma4(acc[11], t2.w, xv);
  }
  float* O = out + (size_t)item * 96 * 9216;
  #pragma unroll
  for (int a = 0; a < 12; ++a) st4(&O[(size_t)(i0 + a) * 9216 + col], acc[a]);
}

// ---------------------------------------------------------------------------
extern "C" void kernel_launch(void* const* d_in, const int* in_sizes, int n_in,
                              void* d_out, int out_size, void* d_ws, size_t ws_size,
                              hipStream_t stream) {
  (void)in_sizes; (void)n_in; (void)out_size;
  const float* x   = (const float*)d_in[0];
  const float* b01 = (const float*)d_in[2];
  const float* b02 = (const float*)d_in[4];
  float* out = (float*)d_out;
  float* ws  = (float*)d_ws;

  const size_t EXTRA = 73728ull*6 + 36864 + 24576*2 + 12288;
  int nch = (ws_size >= ((size_t)64*8*9600 + EXTRA) * sizeof(float)) ? 64 : 32;
  int nsc = 9216 / nch / 48;

  float* Mb  = ws + (size_t)nch * 8 * 9600;
  float* Cb  = Mb  + 73728;
  float* Sb  = Cb  + 36864;    // S1 / S1' ; aliased as TMP
  float* S2b = Sb  + 73728;
  float* S3b = S2b + 73728;
  float* W1b = S3b + 73728;
  float* Tgb = W1b + 73728;
  float* Pb  = Tgb + 73728;
  float* Yb  = Pb  + 24576;
  float* CPb = Yb  + 24576;

  k1_partials<<<dim3(nch*8), 512, 0, stream>>>(x, b01, b02, ws, nch, nsc);
  k2_reduce<<<dim3(160), 128, 0, stream>>>(ws, Mb, Cb, nch);

  // partition 1
  kw_phase<<<dim3(96),256,0,stream>>>(Mb, Mb, nullptr, Sb, SC27,
      nullptr,0,0,0, nullptr,0,0, 0);                                   // S1 = M^2*s
  kw_phase<<<dim3(104),256,0,stream>>>(Sb, Sb, nullptr, S2b, 1.f,
      Cb,4608,48,0, Yb,3072,32, 32);                                    // S2 ; Y = S1*C1
  kw_phase<<<dim3(104),256,0,stream>>>(S2b, S2b, nullptr, S3b, 1.f,
      Yb,3072,32,0, Pb,3072,32, 32);                                    // S3 ; P = S2*Y
  kWproj<32,1><<<dim3(96),256,0,stream>>>(S3b, Pb, W1b, Tgb);           // W1

  // M2 construction
  kw_phase<<<dim3(104),256,0,stream>>>(W1b, Mb, Mb, Sb, 1.f,
      Cb+32,4608,48,1, CPb,1536,16, 16);                                // TMP = M - W1*M ; C2'
  kw_phase<<<dim3(96),256,0,stream>>>(Sb, W1b, Sb, Mb, 1.f,
      nullptr,0,0,0, nullptr,0,0, 0);                                   // M2 = TMP - TMP*W1

  // partition 2
  kw_phase<<<dim3(96),256,0,stream>>>(Mb, Mb, nullptr, Sb, SC27,
      nullptr,0,0,0, nullptr,0,0, 0);                                   // S1' = M2^2*s
  kw_phase<<<dim3(104),256,0,stream>>>(Sb, Sb, nullptr, S2b, 1.f,
      CPb,1536,16,0, Yb,3072,32, 16);                                   // S2' ; Y = S1'*C2'
  kw_phase<<<dim3(104),256,0,stream>>>(S2b, S2b, nullptr, S3b, 1.f,
      Yb,3072,32,0, Pb,3072,32, 16);                                    // S3' ; P = S2'*Y
  kWproj<16,2><<<dim3(96),256,0,stream>>>(S3b, Pb, W1b, Tgb);           // Tg = W1+W2

  k4_out<<<dim3(576), 256, 0, stream>>>(x, Tgb, out);
}